// Round 7
// baseline (384.689 us; speedup 1.0000x reference)
//
#include <hip/hip_runtime.h>
#include <hip/hip_bf16.h>
#include <math.h>

#define N_NODES 50000
#define N_EDGES 800000
#define N_GRAPHS 64
#define NUM_CLASSES 10
#define BIN_W 256
#define NBINS ((N_NODES + BIN_W - 1) / BIN_W) // 196
#define CHUNK 4096
#define NCHUNKS ((N_EDGES + CHUNK - 1) / CHUNK) // 196
#define PACK_BLOCKS 21
#define INIT_BLOCKS 16
#define ROW_BLOCKS ((N_NODES + 127) / 128)    // 391

typedef __attribute__((ext_vector_type(8))) short bf16x8;
typedef __attribute__((ext_vector_type(4))) float f32x4;

__device__ inline unsigned short f2bf(float f) {
    unsigned int u = __float_as_uint(f);
    u += 0x7fffu + ((u >> 16) & 1u);
    return (unsigned short)(u >> 16);
}
__device__ inline void bf8_unpack(uint4 v, float* o) {
    o[0] = __uint_as_float(v.x << 16); o[1] = __uint_as_float(v.x & 0xffff0000u);
    o[2] = __uint_as_float(v.y << 16); o[3] = __uint_as_float(v.y & 0xffff0000u);
    o[4] = __uint_as_float(v.z << 16); o[5] = __uint_as_float(v.z & 0xffff0000u);
    o[6] = __uint_as_float(v.w << 16); o[7] = __uint_as_float(v.w & 0xffff0000u);
}
__device__ inline unsigned int pack2(float a, float b) {
    return (unsigned int)f2bf(a) | ((unsigned int)f2bf(b) << 16);
}

// pack W (fp32 KxN row-major) into MFMA B-fragment layout, one 64-lane group per (nt,kt)
template<int K, int N>
__device__ void packW_dev(const float* __restrict__ W, unsigned short* __restrict__ Wp,
                          int bid, int l) {
    constexpr int KT = K / 32;
    int kt = bid % KT, nt = bid / KT;
    int m = l & 15, quad = l >> 4;
    #pragma unroll
    for (int j = 0; j < 8; j++) {
        int k = kt * 32 + quad * 8 + j;
        int n = nt * 16 + m;
        Wp[((size_t)bid * 64 + l) * 8 + j] = f2bf(W[(size_t)k * N + n]);
    }
}

// ---------------- k_pre: per-chunk bin histogram + weight packing + pooled init ----------------
__global__ __launch_bounds__(256) void k_pre(const int* __restrict__ dst, int* __restrict__ bin_part,
                                             const float* __restrict__ W2, const float* __restrict__ W3,
                                             const float* __restrict__ W4,
                                             unsigned short* wp2, unsigned short* wp3, unsigned short* wp4,
                                             float* pooled) {
    int bid = blockIdx.x, t = threadIdx.x;
    if (bid < NCHUNKS) {
        __shared__ int h[NBINS];
        for (int i = t; i < NBINS; i += 256) h[i] = 0;
        __syncthreads();
        int base = bid * CHUNK;
        int end = base + CHUNK; if (end > N_EDGES) end = N_EDGES;
        for (int e = base + t; e < end; e += 256)
            atomicAdd(&h[dst[e] >> 8], 1);
        __syncthreads();
        for (int i = t; i < NBINS; i += 256) bin_part[bid * NBINS + i] = h[i];
    } else if (bid < NCHUNKS + PACK_BLOCKS) {
        int w = (bid - NCHUNKS) * 4 + (t >> 6);
        int lane = t & 63;
        if (w < 4)       packW_dev<32, 64>(W2, wp2, w, lane);
        else if (w < 20) packW_dev<64, 128>(W3, wp3, w - 4, lane);
        else if (w < 84) packW_dev<128, 256>(W4, wp4, w - 20, lane);
    } else {
        int i = (bid - NCHUNKS - PACK_BLOCKS) * 1024 + t;
        #pragma unroll
        for (int q = 0; q < 4; q++) pooled[i + q * 256] = 0.0f;
    }
}

// ---------------- k_scan: bin scan (block 0) + graph counts (block 1) ----------------
__global__ __launch_bounds__(256) void k_scan(const int* __restrict__ bin_part,
                                              int* bin_start, int* bin_cursor,
                                              const int* __restrict__ batch, float* gcount) {
    int t = threadIdx.x;
    if (blockIdx.x == 0) {
        __shared__ int s[256];
        int v = 0;
        if (t < NBINS)
            for (int c = 0; c < NCHUNKS; c++) v += bin_part[c * NBINS + t];
        s[t] = v; __syncthreads();
        for (int off = 1; off < 256; off <<= 1) {
            int x = (t >= off) ? s[t - off] : 0;
            __syncthreads();
            s[t] += x;
            __syncthreads();
        }
        if (t < NBINS) { bin_start[t] = s[t] - v; bin_cursor[t] = s[t] - v; }
        if (t == 0) bin_start[NBINS] = N_EDGES;
    } else {
        int g = t;
        if (g >= N_GRAPHS) return;
        int lo = 0, hi = N_NODES;
        while (lo < hi) { int m = (lo + hi) >> 1; if (batch[m] < g) lo = m + 1; else hi = m; }
        int start = lo;
        lo = 0; hi = N_NODES;
        while (lo < hi) { int m = (lo + hi) >> 1; if (batch[m] < g + 1) lo = m + 1; else hi = m; }
        gcount[g] = (float)(lo - start);
    }
}

// ---------------- bin-scatter with LDS staging. packed = (dst&255)<<24 | src ----------------
__global__ __launch_bounds__(256) void k_binscatter(const int* __restrict__ src,
                                                    const int* __restrict__ dst,
                                                    int* bin_cursor,
                                                    unsigned int* __restrict__ binned) {
    __shared__ int hist[NBINS];
    __shared__ int off[NBINS];
    __shared__ int bump[NBINS];
    __shared__ int gbase[NBINS];
    __shared__ unsigned int stage[CHUNK];
    __shared__ unsigned char sbin[CHUNK];
    int t = threadIdx.x;
    int base = blockIdx.x * CHUNK;
    int total = N_EDGES - base; if (total > CHUNK) total = CHUNK;
    for (int i = t; i < NBINS; i += 256) { hist[i] = 0; bump[i] = 0; }
    __syncthreads();
    int es[16], ed[16];
    #pragma unroll
    for (int i = 0; i < 16; i++) {
        int e = base + t + i * 256;
        if (e < N_EDGES) { es[i] = src[e]; ed[i] = dst[e]; }
        else ed[i] = -1;
    }
    #pragma unroll
    for (int i = 0; i < 16; i++)
        if (ed[i] >= 0) atomicAdd(&hist[ed[i] >> 8], 1);
    __syncthreads();
    {
        __shared__ int s[256];
        int v = (t < NBINS) ? hist[t] : 0;
        s[t] = v; __syncthreads();
        for (int o = 1; o < 256; o <<= 1) {
            int x = (t >= o) ? s[t - o] : 0;
            __syncthreads();
            s[t] += x;
            __syncthreads();
        }
        if (t < NBINS) off[t] = s[t] - v;
    }
    __syncthreads();
    if (t < NBINS && hist[t] > 0) gbase[t] = atomicAdd(&bin_cursor[t], hist[t]);
    #pragma unroll
    for (int i = 0; i < 16; i++) {
        if (ed[i] >= 0) {
            int b = ed[i] >> 8;
            int lpos = off[b] + atomicAdd(&bump[b], 1);
            stage[lpos] = ((unsigned int)(ed[i] & 255) << 24) | (unsigned int)es[i];
            sbin[lpos] = (unsigned char)b;
        }
    }
    __syncthreads();
    for (int j = t; j < total; j += 256) {
        int b = sbin[j];
        binned[gbase[b] + (j - off[b])] = stage[j];
    }
}

// ---------------- per-bin CSR finalize ----------------
__global__ __launch_bounds__(256) void k_csr(const unsigned int* __restrict__ binned,
                                             const int* __restrict__ bin_start,
                                             int* __restrict__ row_ptr,
                                             float* __restrict__ dinv,
                                             int* __restrict__ csr_src) {
    __shared__ int deg[BIN_W];
    __shared__ int off[BIN_W];
    __shared__ int bump[BIN_W];
    int b = blockIdx.x;
    int t = threadIdx.x;
    deg[t] = 0; bump[t] = 0;
    __syncthreads();
    int e0 = bin_start[b], e1 = bin_start[b + 1];
    for (int e = e0 + t; e < e1; e += 256)
        atomicAdd(&deg[binned[e] >> 24], 1);
    __syncthreads();
    {
        __shared__ int s[256];
        int v = deg[t];
        s[t] = v; __syncthreads();
        for (int o = 1; o < 256; o <<= 1) {
            int x = (t >= o) ? s[t - o] : 0;
            __syncthreads();
            s[t] += x;
            __syncthreads();
        }
        off[t] = s[t] - v;
    }
    __syncthreads();
    int node = b * BIN_W + t;
    if (node < N_NODES) {
        row_ptr[node] = e0 + off[t];
        dinv[node] = rsqrtf((float)(deg[t] + 1));
    }
    if (b == 0 && t == 0) row_ptr[N_NODES] = N_EDGES;
    for (int e = e0 + t; e < e1; e += 256) {
        unsigned int v = binned[e];
        int dl = v >> 24;
        int pos = e0 + off[dl] + atomicAdd(&bump[dl], 1);
        csr_src[pos] = (int)(v & 0x1ffffu);
    }
}

// ---------------- layer 1 fused: agg5 (LDS) + matmul 5->32, bf16 out ----------------
__global__ __launch_bounds__(256) void k_layer1(const float* __restrict__ x,
                                                const int* __restrict__ row_ptr,
                                                const int* __restrict__ csr_src,
                                                const float* __restrict__ dinv,
                                                const float* __restrict__ W1,
                                                const float* __restrict__ b1,
                                                unsigned short* __restrict__ Hout) {
    __shared__ float A5[128 * 5];
    int t = threadIdx.x;
    int row0 = blockIdx.x * 128;
    #pragma unroll
    for (int p = 0; p < 4; p++) {
        int nl = p * 32 + (t >> 3);
        int f = t & 7;
        if (f < 5) {
            int node = row0 + nl;
            float val = 0.0f;
            if (node < N_NODES) {
                float di = dinv[node];
                float acc = di * x[node * 5 + f];
                int e0 = row_ptr[node], e1 = row_ptr[node + 1];
                for (int e = e0; e < e1; e++) {
                    int s = csr_src[e];
                    acc += dinv[s] * x[s * 5 + f];
                }
                val = di * acc;
            }
            A5[nl * 5 + f] = val;
        }
    }
    __syncthreads();
    int j = t & 31, g = t >> 5;      // g: 0..7 -> 16-row groups
    float b = b1[j];
    float wcol[5];
    #pragma unroll
    for (int k = 0; k < 5; k++) wcol[k] = W1[k * 32 + j];
    #pragma unroll
    for (int r = 0; r < 16; r++) {
        int rl = g * 16 + r;
        int row = row0 + rl;
        if (row < N_NODES) {
            float acc = b;
            #pragma unroll
            for (int k = 0; k < 5; k++) acc += A5[rl * 5 + k] * wcol[k];
            Hout[(size_t)row * 32 + j] = f2bf(fmaxf(acc, 0.0f));
        }
    }
}

// ---------------- fused layer: aggregate (LDS) + MFMA GEMM + (opt) pool ----------------
template<int K, int N, bool POOL>
__global__ __launch_bounds__(256) void k_layer(const unsigned short* __restrict__ Hin,
                                               const int* __restrict__ row_ptr,
                                               const int* __restrict__ csr_src,
                                               const float* __restrict__ dinv,
                                               const unsigned short* __restrict__ Wp,
                                               const float* __restrict__ bias,
                                               unsigned short* __restrict__ Hout,
                                               const int* __restrict__ batch,
                                               float* __restrict__ pooled) {
    constexpr int KT = K / 32, NT = N / 16, DV = K / 8, KP = K + 8;
    __shared__ unsigned short As[128 * KP];
    __shared__ float pl[POOL ? 1024 : 4];
    __shared__ int bb[POOL ? 128 : 4];
    __shared__ int s_gmin;
    int t = threadIdx.x;
    int row0 = blockIdx.x * 128;
    if constexpr (POOL) {
        for (int i = t; i < 1024; i += 256) pl[i] = 0.0f;
        if (t < 128) bb[t] = batch[min(row0 + t, N_NODES - 1)];
        if (t == 0) s_gmin = batch[min(row0, N_NODES - 1)];
    }
    // phase 1: aggregate 128 nodes into LDS (bf16)
    const uint4* h4 = (const uint4*)Hin;
    #pragma unroll
    for (int p = 0; p < 128 * DV / 256; p++) {
        int nl = p * (256 / DV) + t / DV;
        int f = t % DV;
        int node = row0 + nl;
        uint4 o = {0u, 0u, 0u, 0u};
        if (node < N_NODES) {
            float di = dinv[node];
            float selfv[8];
            bf8_unpack(h4[(size_t)node * DV + f], selfv);
            float acc0[8], acc1[8];
            #pragma unroll
            for (int i = 0; i < 8; i++) { acc0[i] = di * selfv[i]; acc1[i] = 0.0f; }
            int e0 = row_ptr[node], e1 = row_ptr[node + 1];
            int e = e0;
            for (; e + 1 < e1; e += 2) {
                int s0 = csr_src[e], s1 = csr_src[e + 1];
                float w0 = dinv[s0], w1 = dinv[s1];
                uint4 u0 = h4[(size_t)s0 * DV + f];
                uint4 u1 = h4[(size_t)s1 * DV + f];
                float t0[8], t1[8];
                bf8_unpack(u0, t0);
                bf8_unpack(u1, t1);
                #pragma unroll
                for (int i = 0; i < 8; i++) { acc0[i] += w0 * t0[i]; acc1[i] += w1 * t1[i]; }
            }
            if (e < e1) {
                int s0 = csr_src[e];
                float w0 = dinv[s0];
                float t0[8];
                bf8_unpack(h4[(size_t)s0 * DV + f], t0);
                #pragma unroll
                for (int i = 0; i < 8; i++) acc0[i] += w0 * t0[i];
            }
            o.x = pack2(di * (acc0[0] + acc1[0]), di * (acc0[1] + acc1[1]));
            o.y = pack2(di * (acc0[2] + acc1[2]), di * (acc0[3] + acc1[3]));
            o.z = pack2(di * (acc0[4] + acc1[4]), di * (acc0[5] + acc1[5]));
            o.w = pack2(di * (acc0[6] + acc1[6]), di * (acc0[7] + acc1[7]));
        }
        *(uint4*)&As[nl * KP + f * 8] = o;
    }
    __syncthreads();
    // phase 2: MFMA from LDS
    int wave = t >> 6, lane = t & 63;
    int m = lane & 15, quad = lane >> 4;
    bf16x8 a0[KT], a1[KT];
    #pragma unroll
    for (int kt = 0; kt < KT; kt++) {
        a0[kt] = *(const bf16x8*)&As[(wave * 32 + m) * KP + kt * 32 + quad * 8];
        a1[kt] = *(const bf16x8*)&As[(wave * 32 + 16 + m) * KP + kt * 32 + quad * 8];
    }
    const bf16x8* Bp = (const bf16x8*)Wp;
    int gmin = 0;
    if constexpr (POOL) gmin = s_gmin;
    for (int nt = 0; nt < NT; nt++) {
        f32x4 c0 = {0.f, 0.f, 0.f, 0.f}, c1 = {0.f, 0.f, 0.f, 0.f};
        #pragma unroll
        for (int kt = 0; kt < KT; kt++) {
            bf16x8 b = Bp[(size_t)(nt * KT + kt) * 64 + lane];
            c0 = __builtin_amdgcn_mfma_f32_16x16x32_bf16(a0[kt], b, c0, 0, 0, 0);
            c1 = __builtin_amdgcn_mfma_f32_16x16x32_bf16(a1[kt], b, c1, 0, 0, 0);
        }
        int col = nt * 16 + m;
        float bv = bias[col];
        #pragma unroll
        for (int r = 0; r < 4; r++) {
            int rl0 = wave * 32 + quad * 4 + r;
            int rl1 = rl0 + 16;
            float v0 = fmaxf(c0[r] + bv, 0.0f);
            float v1 = fmaxf(c1[r] + bv, 0.0f);
            if constexpr (POOL) {
                if (row0 + rl0 < N_NODES) {
                    int s = bb[rl0] - gmin;
                    if (s < 4) atomicAdd(&pl[s * 256 + col], v0);
                    else atomicAdd(&pooled[(size_t)bb[rl0] * 256 + col], v0);
                }
                if (row0 + rl1 < N_NODES) {
                    int s = bb[rl1] - gmin;
                    if (s < 4) atomicAdd(&pl[s * 256 + col], v1);
                    else atomicAdd(&pooled[(size_t)bb[rl1] * 256 + col], v1);
                }
            } else {
                if (row0 + rl0 < N_NODES) Hout[(size_t)(row0 + rl0) * N + col] = f2bf(v0);
                if (row0 + rl1 < N_NODES) Hout[(size_t)(row0 + rl1) * N + col] = f2bf(v1);
            }
        }
    }
    if constexpr (POOL) {
        __syncthreads();
        int lastl = N_NODES - 1 - row0; if (lastl > 127) lastl = 127;
        int span = bb[lastl] - gmin + 1;
        if (span > 4) span = 4;
        for (int s = 0; s < span; s++)
            atomicAdd(&pooled[(size_t)(gmin + s) * 256 + t], pl[s * 256 + t]);
    }
}

// ---------------- FC + log_softmax (one wave per graph) ----------------
__global__ void k_final(const float* __restrict__ pooled, const float* __restrict__ gcount,
                        const float* __restrict__ fcW, const float* __restrict__ fcb,
                        float* __restrict__ out) {
    int g = blockIdx.x;
    int t = threadIdx.x;                 // 0..63
    float p[4];
    #pragma unroll
    for (int m = 0; m < 4; m++) p[m] = pooled[g * 256 + t + 64 * m];
    float inv = 1.0f / fmaxf(gcount[g], 1.0f);
    float logits[NUM_CLASSES];
    #pragma unroll
    for (int j = 0; j < NUM_CLASSES; j++) {
        float s = 0.0f;
        #pragma unroll
        for (int m = 0; m < 4; m++) s += p[m] * fcW[(t + 64 * m) * NUM_CLASSES + j];
        for (int off = 32; off > 0; off >>= 1) s += __shfl_xor(s, off);
        logits[j] = s * inv + fcb[j];
    }
    float mx = logits[0];
    #pragma unroll
    for (int j = 1; j < NUM_CLASSES; j++) mx = fmaxf(mx, logits[j]);
    float se = 0.0f;
    #pragma unroll
    for (int j = 0; j < NUM_CLASSES; j++) se += expf(logits[j] - mx);
    float lse = mx + logf(se);
    if (t < NUM_CLASSES) out[g * NUM_CLASSES + t] = logits[t] - lse;
}

extern "C" void kernel_launch(void* const* d_in, const int* in_sizes, int n_in,
                              void* d_out, int out_size, void* d_ws, size_t ws_size,
                              hipStream_t stream) {
    const float* x     = (const float*)d_in[0];
    const int*   ei    = (const int*)d_in[1];
    const int*   src   = ei;
    const int*   dst   = ei + N_EDGES;
    const int*   batch = (const int*)d_in[2];
    const float* W1 = (const float*)d_in[3];  const float* b1 = (const float*)d_in[4];
    const float* W2 = (const float*)d_in[5];  const float* b2 = (const float*)d_in[6];
    const float* W3 = (const float*)d_in[7];  const float* b3 = (const float*)d_in[8];
    const float* W4 = (const float*)d_in[9];  const float* b4 = (const float*)d_in[10];
    const float* fcW = (const float*)d_in[11]; const float* fcb = (const float*)d_in[12];
    float* out = (float*)d_out;

    char* ws = (char*)d_ws;
    unsigned short* buf1 = (unsigned short*)ws; ws += (size_t)N_NODES * 256 * 2;
    unsigned short* buf2 = (unsigned short*)ws; ws += (size_t)N_NODES * 256 * 2;
    float* dinv     = (float*)ws; ws += (size_t)N_NODES * 4;
    int*   row_ptr  = (int*)ws;   ws += (size_t)(N_NODES + 4) * 4;
    int*   csr_src  = (int*)ws;   ws += (size_t)N_EDGES * 4;
    unsigned int* binned = (unsigned int*)ws; ws += (size_t)N_EDGES * 4;
    int*   bin_part = (int*)ws;   ws += (size_t)NCHUNKS * NBINS * 4;
    int*   bin_start= (int*)ws;   ws += (NBINS + 4) * 4;
    int*   bin_cur  = (int*)ws;   ws += (NBINS + 4) * 4;
    float* pooled   = (float*)ws; ws += (size_t)N_GRAPHS * 256 * 4;
    float* gcount   = (float*)ws; ws += 256 * 4;
    unsigned short* wp2 = (unsigned short*)ws; ws += 32 * 64 * 2;
    unsigned short* wp3 = (unsigned short*)ws; ws += 64 * 128 * 2;
    unsigned short* wp4 = (unsigned short*)ws; ws += 128 * 256 * 2;

    const int TB = 256;
    k_pre<<<NCHUNKS + PACK_BLOCKS + INIT_BLOCKS, TB, 0, stream>>>(dst, bin_part, W2, W3, W4,
                                                                  wp2, wp3, wp4, pooled);
    k_scan<<<2, TB, 0, stream>>>(bin_part, bin_start, bin_cur, batch, gcount);
    k_binscatter<<<NCHUNKS, TB, 0, stream>>>(src, dst, bin_cur, binned);
    k_csr<<<NBINS, TB, 0, stream>>>(binned, bin_start, row_ptr, dinv, csr_src);

    k_layer1<<<ROW_BLOCKS, TB, 0, stream>>>(x, row_ptr, csr_src, dinv, W1, b1, buf1);
    k_layer<32, 64, false><<<ROW_BLOCKS, TB, 0, stream>>>(buf1, row_ptr, csr_src, dinv,
                                                          wp2, b2, buf2, nullptr, nullptr);
    k_layer<64, 128, false><<<ROW_BLOCKS, TB, 0, stream>>>(buf2, row_ptr, csr_src, dinv,
                                                           wp3, b3, buf1, nullptr, nullptr);
    k_layer<128, 256, true><<<ROW_BLOCKS, TB, 0, stream>>>(buf1, row_ptr, csr_src, dinv,
                                                           wp4, b4, nullptr, batch, pooled);
    k_final<<<N_GRAPHS, 64, 0, stream>>>(pooled, gcount, fcW, fcb, out);
}

// Round 8
// 314.178 us; speedup vs baseline: 1.2244x; 1.2244x over previous
//
#include <hip/hip_runtime.h>
#include <hip/hip_bf16.h>
#include <math.h>

#define N_NODES 50000
#define N_EDGES 800000
#define N_GRAPHS 64
#define NUM_CLASSES 10
#define MTILES ((N_NODES + 15) / 16)          // 3125
#define BIN_W 256
#define NBINS ((N_NODES + BIN_W - 1) / BIN_W) // 196
#define CHUNK 4096
#define NCHUNKS ((N_EDGES + CHUNK - 1) / CHUNK) // 196
#define PACK_BLOCKS 21
#define INIT_BLOCKS 16

typedef __attribute__((ext_vector_type(8))) short bf16x8;
typedef __attribute__((ext_vector_type(4))) float f32x4;

__device__ inline unsigned short f2bf(float f) {
    unsigned int u = __float_as_uint(f);
    u += 0x7fffu + ((u >> 16) & 1u);
    return (unsigned short)(u >> 16);
}
__device__ inline float bf2f(unsigned short v) {
    return __uint_as_float((unsigned int)v << 16);
}
__device__ inline void bf8_unpack(uint4 v, float* o) {
    o[0] = __uint_as_float(v.x << 16); o[1] = __uint_as_float(v.x & 0xffff0000u);
    o[2] = __uint_as_float(v.y << 16); o[3] = __uint_as_float(v.y & 0xffff0000u);
    o[4] = __uint_as_float(v.z << 16); o[5] = __uint_as_float(v.z & 0xffff0000u);
    o[6] = __uint_as_float(v.w << 16); o[7] = __uint_as_float(v.w & 0xffff0000u);
}
__device__ inline unsigned int pack2(float a, float b) {
    return (unsigned int)f2bf(a) | ((unsigned int)f2bf(b) << 16);
}

// pack W (fp32 KxN row-major) into MFMA B-fragment layout, one 64-lane group per (nt,kt)
template<int K, int N>
__device__ void packW_dev(const float* __restrict__ W, unsigned short* __restrict__ Wp,
                          int bid, int l) {
    constexpr int KT = K / 32;
    int kt = bid % KT, nt = bid / KT;
    int m = l & 15, quad = l >> 4;
    #pragma unroll
    for (int j = 0; j < 8; j++) {
        int k = kt * 32 + quad * 8 + j;
        int n = nt * 16 + m;
        Wp[((size_t)bid * 64 + l) * 8 + j] = f2bf(W[(size_t)k * N + n]);
    }
}

// ---------------- k_pre: per-chunk bin histogram + weight packing + pooled init ----------------
__global__ __launch_bounds__(256) void k_pre(const int* __restrict__ dst, int* __restrict__ bin_part,
                                             const float* __restrict__ W2, const float* __restrict__ W3,
                                             const float* __restrict__ W4,
                                             unsigned short* wp2, unsigned short* wp3, unsigned short* wp4,
                                             float* pooled) {
    int bid = blockIdx.x, t = threadIdx.x;
    if (bid < NCHUNKS) {
        __shared__ int h[NBINS];
        for (int i = t; i < NBINS; i += 256) h[i] = 0;
        __syncthreads();
        int base = bid * CHUNK;
        int end = base + CHUNK; if (end > N_EDGES) end = N_EDGES;
        for (int e = base + t; e < end; e += 256)
            atomicAdd(&h[dst[e] >> 8], 1);
        __syncthreads();
        for (int i = t; i < NBINS; i += 256) bin_part[bid * NBINS + i] = h[i];
    } else if (bid < NCHUNKS + PACK_BLOCKS) {
        int w = (bid - NCHUNKS) * 4 + (t >> 6);
        int lane = t & 63;
        if (w < 4)       packW_dev<32, 64>(W2, wp2, w, lane);
        else if (w < 20) packW_dev<64, 128>(W3, wp3, w - 4, lane);
        else if (w < 84) packW_dev<128, 256>(W4, wp4, w - 20, lane);
    } else {
        int i = (bid - NCHUNKS - PACK_BLOCKS) * 1024 + t;
        #pragma unroll
        for (int q = 0; q < 4; q++) pooled[i + q * 256] = 0.0f;
    }
}

// ---------------- k_scan: bin scan (block 0) + graph counts (block 1) ----------------
__global__ __launch_bounds__(256) void k_scan(const int* __restrict__ bin_part,
                                              int* bin_start, int* bin_cursor,
                                              const int* __restrict__ batch, float* gcount) {
    int t = threadIdx.x;
    if (blockIdx.x == 0) {
        __shared__ int s[256];
        int v = 0;
        if (t < NBINS)
            for (int c = 0; c < NCHUNKS; c++) v += bin_part[c * NBINS + t];
        s[t] = v; __syncthreads();
        for (int off = 1; off < 256; off <<= 1) {
            int x = (t >= off) ? s[t - off] : 0;
            __syncthreads();
            s[t] += x;
            __syncthreads();
        }
        if (t < NBINS) { bin_start[t] = s[t] - v; bin_cursor[t] = s[t] - v; }
        if (t == 0) bin_start[NBINS] = N_EDGES;
    } else {
        int g = t;
        if (g >= N_GRAPHS) return;
        int lo = 0, hi = N_NODES;
        while (lo < hi) { int m = (lo + hi) >> 1; if (batch[m] < g) lo = m + 1; else hi = m; }
        int start = lo;
        lo = 0; hi = N_NODES;
        while (lo < hi) { int m = (lo + hi) >> 1; if (batch[m] < g + 1) lo = m + 1; else hi = m; }
        gcount[g] = (float)(lo - start);
    }
}

// ---------------- bin-scatter with LDS staging. packed = (dst&255)<<24 | src ----------------
__global__ __launch_bounds__(256) void k_binscatter(const int* __restrict__ src,
                                                    const int* __restrict__ dst,
                                                    int* bin_cursor,
                                                    unsigned int* __restrict__ binned) {
    __shared__ int hist[NBINS];
    __shared__ int off[NBINS];
    __shared__ int bump[NBINS];
    __shared__ int gbase[NBINS];
    __shared__ unsigned int stage[CHUNK];
    __shared__ unsigned char sbin[CHUNK];
    int t = threadIdx.x;
    int base = blockIdx.x * CHUNK;
    int total = N_EDGES - base; if (total > CHUNK) total = CHUNK;
    for (int i = t; i < NBINS; i += 256) { hist[i] = 0; bump[i] = 0; }
    __syncthreads();
    int es[16], ed[16];
    #pragma unroll
    for (int i = 0; i < 16; i++) {
        int e = base + t + i * 256;
        if (e < N_EDGES) { es[i] = src[e]; ed[i] = dst[e]; }
        else ed[i] = -1;
    }
    #pragma unroll
    for (int i = 0; i < 16; i++)
        if (ed[i] >= 0) atomicAdd(&hist[ed[i] >> 8], 1);
    __syncthreads();
    {
        __shared__ int s[256];
        int v = (t < NBINS) ? hist[t] : 0;
        s[t] = v; __syncthreads();
        for (int o = 1; o < 256; o <<= 1) {
            int x = (t >= o) ? s[t - o] : 0;
            __syncthreads();
            s[t] += x;
            __syncthreads();
        }
        if (t < NBINS) off[t] = s[t] - v;
    }
    __syncthreads();
    if (t < NBINS && hist[t] > 0) gbase[t] = atomicAdd(&bin_cursor[t], hist[t]);
    #pragma unroll
    for (int i = 0; i < 16; i++) {
        if (ed[i] >= 0) {
            int b = ed[i] >> 8;
            int lpos = off[b] + atomicAdd(&bump[b], 1);
            stage[lpos] = ((unsigned int)(ed[i] & 255) << 24) | (unsigned int)es[i];
            sbin[lpos] = (unsigned char)b;
        }
    }
    __syncthreads();
    for (int j = t; j < total; j += 256) {
        int b = sbin[j];
        binned[gbase[b] + (j - off[b])] = stage[j];
    }
}

// ---------------- per-bin CSR finalize ----------------
__global__ __launch_bounds__(256) void k_csr(const unsigned int* __restrict__ binned,
                                             const int* __restrict__ bin_start,
                                             int* __restrict__ row_ptr,
                                             float* __restrict__ dinv,
                                             int* __restrict__ csr_src) {
    __shared__ int deg[BIN_W];
    __shared__ int off[BIN_W];
    __shared__ int bump[BIN_W];
    int b = blockIdx.x;
    int t = threadIdx.x;
    deg[t] = 0; bump[t] = 0;
    __syncthreads();
    int e0 = bin_start[b], e1 = bin_start[b + 1];
    for (int e = e0 + t; e < e1; e += 256)
        atomicAdd(&deg[binned[e] >> 24], 1);
    __syncthreads();
    {
        __shared__ int s[256];
        int v = deg[t];
        s[t] = v; __syncthreads();
        for (int o = 1; o < 256; o <<= 1) {
            int x = (t >= o) ? s[t - o] : 0;
            __syncthreads();
            s[t] += x;
            __syncthreads();
        }
        off[t] = s[t] - v;
    }
    __syncthreads();
    int node = b * BIN_W + t;
    if (node < N_NODES) {
        row_ptr[node] = e0 + off[t];
        dinv[node] = rsqrtf((float)(deg[t] + 1));
    }
    if (b == 0 && t == 0) row_ptr[N_NODES] = N_EDGES;
    for (int e = e0 + t; e < e1; e += 256) {
        unsigned int v = binned[e];
        int dl = v >> 24;
        int pos = e0 + off[dl] + atomicAdd(&bump[dl], 1);
        csr_src[pos] = (int)(v & 0x1ffffu);
    }
}

// ---------------- aggregate (fp32 input, D=5), 8 threads/node ----------------
__global__ void k_agg5(const float* __restrict__ h, const int* __restrict__ row_ptr,
                       const int* __restrict__ csr_src,
                       const float* __restrict__ dinv, float* __restrict__ out) {
    int t = threadIdx.x;
    int f = t & 7;
    int g = t >> 3;
    int node = blockIdx.x * 32 + g;
    if (node >= N_NODES || f >= 5) return;
    float di = dinv[node];
    float acc = di * h[node * 5 + f];
    int e0 = row_ptr[node], e1 = row_ptr[node + 1];
    for (int e = e0; e < e1; e++) {
        int s = csr_src[e];
        acc += dinv[s] * h[s * 5 + f];
    }
    out[node * 5 + f] = di * acc;
}

// ---------------- aggregate, bf16 in -> bf16 out ----------------
template<int D>
__global__ void k_aggb(const unsigned short* __restrict__ h, const int* __restrict__ row_ptr,
                       const int* __restrict__ csr_src,
                       const float* __restrict__ dinv, unsigned short* __restrict__ out) {
    constexpr int DV = D / 8;
    constexpr int G = 256 / DV;
    const uint4* h4 = (const uint4*)h;
    int t = threadIdx.x;
    int f = t % DV;
    int g = t / DV;
    int node = blockIdx.x * G + g;
    if (node >= N_NODES) return;
    float di = dinv[node];
    float selfv[8];
    bf8_unpack(h4[(size_t)node * DV + f], selfv);
    float acc0[8], acc1[8];
    #pragma unroll
    for (int i = 0; i < 8; i++) { acc0[i] = di * selfv[i]; acc1[i] = 0.0f; }
    int e0 = row_ptr[node], e1 = row_ptr[node + 1];
    int e = e0;
    for (; e + 1 < e1; e += 2) {
        int s0 = csr_src[e], s1 = csr_src[e + 1];
        float w0 = dinv[s0], w1 = dinv[s1];
        uint4 u0 = h4[(size_t)s0 * DV + f];
        uint4 u1 = h4[(size_t)s1 * DV + f];
        float t0[8], t1[8];
        bf8_unpack(u0, t0);
        bf8_unpack(u1, t1);
        #pragma unroll
        for (int i = 0; i < 8; i++) { acc0[i] += w0 * t0[i]; acc1[i] += w1 * t1[i]; }
    }
    if (e < e1) {
        int s0 = csr_src[e];
        float w0 = dinv[s0];
        float t0[8];
        bf8_unpack(h4[(size_t)s0 * DV + f], t0);
        #pragma unroll
        for (int i = 0; i < 8; i++) acc0[i] += w0 * t0[i];
    }
    uint4 o;
    o.x = pack2(di * (acc0[0] + acc1[0]), di * (acc0[1] + acc1[1]));
    o.y = pack2(di * (acc0[2] + acc1[2]), di * (acc0[3] + acc1[3]));
    o.z = pack2(di * (acc0[4] + acc1[4]), di * (acc0[5] + acc1[5]));
    o.w = pack2(di * (acc0[6] + acc1[6]), di * (acc0[7] + acc1[7]));
    ((uint4*)out)[(size_t)node * DV + f] = o;
}

// ---------------- layer-1 matmul (K=5): bf16 out = relu(Hin @ W + b) ----------------
template<int DIN, int DOUT>
__global__ void k_matmul(const float* __restrict__ Hin, const float* __restrict__ W,
                         const float* __restrict__ bias, unsigned short* __restrict__ Hout) {
    constexpr int G = 256 / DOUT;
    constexpr int ROWS = 16;
    constexpr int RPB = G * ROWS;
    __shared__ float lds[RPB * DIN];
    int t = threadIdx.x;
    int row0 = blockIdx.x * RPB;
    const int base = row0 * DIN;
    const int lim = N_NODES * DIN - base;
    for (int idx = t; idx < RPB * DIN; idx += 256)
        lds[idx] = (idx < lim) ? Hin[base + idx] : 0.0f;
    __syncthreads();
    int j = t % DOUT;
    int g = t / DOUT;
    float b = bias[j];
    float acc[ROWS];
    #pragma unroll
    for (int r = 0; r < ROWS; r++) acc[r] = 0.0f;
    for (int k = 0; k < DIN; k++) {
        float w = W[k * DOUT + j];
        #pragma unroll
        for (int r = 0; r < ROWS; r++)
            acc[r] += lds[(g * ROWS + r) * DIN + k] * w;
    }
    #pragma unroll
    for (int r = 0; r < ROWS; r++) {
        int gr = row0 + g * ROWS + r;
        if (gr < N_NODES) {
            float v = acc[r] + b;
            Hout[gr * DOUT + j] = f2bf(v > 0.0f ? v : 0.0f);
        }
    }
}

// ---------------- MFMA GEMM: C = relu(A @ W + b), bf16 out ----------------
template<int K, int N>
__global__ __launch_bounds__(256) void k_gemm_mfma(const unsigned short* __restrict__ A,
                                                   const unsigned short* __restrict__ Wp,
                                                   const float* __restrict__ bias,
                                                   unsigned short* __restrict__ C) {
    constexpr int KT = K / 32, NT = N / 16;
    int wave = threadIdx.x >> 6, lane = threadIdx.x & 63;
    int wid = blockIdx.x * 4 + wave;
    int mt0 = wid * 2;
    if (mt0 >= MTILES) return;
    bool two = (mt0 + 1) < MTILES;
    int m = lane & 15, quad = lane >> 4;
    bf16x8 a0[KT], a1[KT];
    #pragma unroll
    for (int kt = 0; kt < KT; kt++) {
        a0[kt] = *(const bf16x8*)(A + (size_t)(mt0 * 16 + m) * K + kt * 32 + quad * 8);
        a1[kt] = *(const bf16x8*)(A + (size_t)((mt0 + 1) * 16 + m) * K + kt * 32 + quad * 8);
    }
    const bf16x8* Bp = (const bf16x8*)Wp;
    for (int nt = 0; nt < NT; nt++) {
        f32x4 c0 = {0.f, 0.f, 0.f, 0.f}, c1 = {0.f, 0.f, 0.f, 0.f};
        #pragma unroll
        for (int kt = 0; kt < KT; kt++) {
            bf16x8 b = Bp[(size_t)(nt * KT + kt) * 64 + lane];
            c0 = __builtin_amdgcn_mfma_f32_16x16x32_bf16(a0[kt], b, c0, 0, 0, 0);
            c1 = __builtin_amdgcn_mfma_f32_16x16x32_bf16(a1[kt], b, c1, 0, 0, 0);
        }
        int col = nt * 16 + m;
        float bv = bias[col];
        #pragma unroll
        for (int r = 0; r < 4; r++) {
            int row0 = mt0 * 16 + quad * 4 + r;
            float v0 = fmaxf(c0[r] + bv, 0.f);
            C[(size_t)row0 * N + col] = f2bf(v0);
            if (two) {
                int row1 = row0 + 16;
                float v1 = fmaxf(c1[r] + bv, 0.f);
                C[(size_t)row1 * N + col] = f2bf(v1);
            }
        }
    }
}

// ---------------- L4 GEMM (128->256) with fused mean-pool accumulate ----------------
__global__ __launch_bounds__(256) void k_gemm_pool(const unsigned short* __restrict__ A,
                                                   const unsigned short* __restrict__ Wp,
                                                   const float* __restrict__ bias,
                                                   const int* __restrict__ batch,
                                                   float* __restrict__ pooled) {
    constexpr int K = 128, N = 256, KT = 4, NT = 16;
    __shared__ float pl[4 * 256];
    __shared__ int bb[128];
    __shared__ int s_gmin;
    int t = threadIdx.x;
    int wave = t >> 6, lane = t & 63;
    int row0b = blockIdx.x * 128;
    for (int i = t; i < 1024; i += 256) pl[i] = 0.0f;
    if (t < 128) bb[t] = batch[min(row0b + t, N_NODES - 1)];
    if (t == 0) s_gmin = batch[min(row0b, N_NODES - 1)];
    __syncthreads();
    int wid = blockIdx.x * 4 + wave;
    int mt0 = wid * 2;
    int m = lane & 15, quad = lane >> 4;
    // clamp rows for OOB loads (adds guarded later)
    int ra = min(mt0 * 16 + m, N_NODES - 1);
    int rb = min(mt0 * 16 + 16 + m, N_NODES - 1);
    bf16x8 a0[KT], a1[KT];
    #pragma unroll
    for (int kt = 0; kt < KT; kt++) {
        a0[kt] = *(const bf16x8*)(A + (size_t)ra * K + kt * 32 + quad * 8);
        a1[kt] = *(const bf16x8*)(A + (size_t)rb * K + kt * 32 + quad * 8);
    }
    const bf16x8* Bp = (const bf16x8*)Wp;
    int gmin = s_gmin;
    for (int nt = 0; nt < NT; nt++) {
        f32x4 c0 = {0.f, 0.f, 0.f, 0.f}, c1 = {0.f, 0.f, 0.f, 0.f};
        #pragma unroll
        for (int kt = 0; kt < KT; kt++) {
            bf16x8 b = Bp[(size_t)(nt * KT + kt) * 64 + lane];
            c0 = __builtin_amdgcn_mfma_f32_16x16x32_bf16(a0[kt], b, c0, 0, 0, 0);
            c1 = __builtin_amdgcn_mfma_f32_16x16x32_bf16(a1[kt], b, c1, 0, 0, 0);
        }
        int col = nt * 16 + m;
        float bv = bias[col];
        #pragma unroll
        for (int r = 0; r < 4; r++) {
            int rl0 = (mt0 * 16 + quad * 4 + r) - row0b;   // local row 0..127
            int rl1 = rl0 + 16;
            float v0 = fmaxf(c0[r] + bv, 0.0f);
            float v1 = fmaxf(c1[r] + bv, 0.0f);
            if (row0b + rl0 < N_NODES) {
                int s = bb[rl0] - gmin;
                if (s < 4) atomicAdd(&pl[s * 256 + col], v0);
                else atomicAdd(&pooled[(size_t)bb[rl0] * 256 + col], v0);
            }
            if (row0b + rl1 < N_NODES) {
                int s = bb[rl1] - gmin;
                if (s < 4) atomicAdd(&pl[s * 256 + col], v1);
                else atomicAdd(&pooled[(size_t)bb[rl1] * 256 + col], v1);
            }
        }
    }
    __syncthreads();
    int lastl = N_NODES - 1 - row0b; if (lastl > 127) lastl = 127;
    int span = bb[lastl] - gmin + 1;
    if (span > 4) span = 4;
    for (int s = 0; s < span; s++)
        atomicAdd(&pooled[(size_t)(gmin + s) * 256 + t], pl[s * 256 + t]);
}

// ---------------- FC + log_softmax (one wave per graph) ----------------
__global__ void k_final(const float* __restrict__ pooled, const float* __restrict__ gcount,
                        const float* __restrict__ fcW, const float* __restrict__ fcb,
                        float* __restrict__ out) {
    int g = blockIdx.x;
    int t = threadIdx.x;                 // 0..63
    float p[4];
    #pragma unroll
    for (int m = 0; m < 4; m++) p[m] = pooled[g * 256 + t + 64 * m];
    float inv = 1.0f / fmaxf(gcount[g], 1.0f);
    float logits[NUM_CLASSES];
    #pragma unroll
    for (int j = 0; j < NUM_CLASSES; j++) {
        float s = 0.0f;
        #pragma unroll
        for (int m = 0; m < 4; m++) s += p[m] * fcW[(t + 64 * m) * NUM_CLASSES + j];
        for (int off = 32; off > 0; off >>= 1) s += __shfl_xor(s, off);
        logits[j] = s * inv + fcb[j];
    }
    float mx = logits[0];
    #pragma unroll
    for (int j = 1; j < NUM_CLASSES; j++) mx = fmaxf(mx, logits[j]);
    float se = 0.0f;
    #pragma unroll
    for (int j = 0; j < NUM_CLASSES; j++) se += expf(logits[j] - mx);
    float lse = mx + logf(se);
    if (t < NUM_CLASSES) out[g * NUM_CLASSES + t] = logits[t] - lse;
}

extern "C" void kernel_launch(void* const* d_in, const int* in_sizes, int n_in,
                              void* d_out, int out_size, void* d_ws, size_t ws_size,
                              hipStream_t stream) {
    const float* x     = (const float*)d_in[0];
    const int*   ei    = (const int*)d_in[1];
    const int*   src   = ei;
    const int*   dst   = ei + N_EDGES;
    const int*   batch = (const int*)d_in[2];
    const float* W1 = (const float*)d_in[3];  const float* b1 = (const float*)d_in[4];
    const float* W2 = (const float*)d_in[5];  const float* b2 = (const float*)d_in[6];
    const float* W3 = (const float*)d_in[7];  const float* b3 = (const float*)d_in[8];
    const float* W4 = (const float*)d_in[9];  const float* b4 = (const float*)d_in[10];
    const float* fcW = (const float*)d_in[11]; const float* fcb = (const float*)d_in[12];
    float* out = (float*)d_out;

    char* ws = (char*)d_ws;
    unsigned short* buf1 = (unsigned short*)ws; ws += (size_t)N_NODES * 256 * 2;
    unsigned short* buf2 = (unsigned short*)ws; ws += (size_t)N_NODES * 256 * 2;
    float* bufA     = (float*)ws; ws += (size_t)N_NODES * 8 * 4;     // agg5 out (fp32, D=5 rounded up)
    float* dinv     = (float*)ws; ws += (size_t)N_NODES * 4;
    int*   row_ptr  = (int*)ws;   ws += (size_t)(N_NODES + 4) * 4;
    int*   csr_src  = (int*)ws;   ws += (size_t)N_EDGES * 4;
    unsigned int* binned = (unsigned int*)ws; ws += (size_t)N_EDGES * 4;
    int*   bin_part = (int*)ws;   ws += (size_t)NCHUNKS * NBINS * 4;
    int*   bin_start= (int*)ws;   ws += (NBINS + 4) * 4;
    int*   bin_cur  = (int*)ws;   ws += (NBINS + 4) * 4;
    float* pooled   = (float*)ws; ws += (size_t)N_GRAPHS * 256 * 4;
    float* gcount   = (float*)ws; ws += 256 * 4;
    unsigned short* wp2 = (unsigned short*)ws; ws += 32 * 64 * 2;
    unsigned short* wp3 = (unsigned short*)ws; ws += 64 * 128 * 2;
    unsigned short* wp4 = (unsigned short*)ws; ws += 128 * 256 * 2;

    const int TB = 256;
    const int GEMM_BLOCKS = ((MTILES + 1) / 2 + 3) / 4;   // 391

    k_pre<<<NCHUNKS + PACK_BLOCKS + INIT_BLOCKS, TB, 0, stream>>>(dst, bin_part, W2, W3, W4,
                                                                  wp2, wp3, wp4, pooled);
    k_scan<<<2, TB, 0, stream>>>(bin_part, bin_start, bin_cur, batch, gcount);
    k_binscatter<<<NCHUNKS, TB, 0, stream>>>(src, dst, bin_cur, binned);
    k_csr<<<NBINS, TB, 0, stream>>>(binned, bin_start, row_ptr, dinv, csr_src);

    // layer 1: agg(x)[5] -> mm 5->32 (bf16 out)
    k_agg5<<<(N_NODES + 31) / 32, TB, 0, stream>>>(x, row_ptr, csr_src, dinv, bufA);
    k_matmul<5, 32><<<(N_NODES + 127) / 128, TB, 0, stream>>>(bufA, W1, b1, buf1);
    // layer 2
    k_aggb<32><<<(N_NODES + 63) / 64, TB, 0, stream>>>(buf1, row_ptr, csr_src, dinv, buf2);
    k_gemm_mfma<32, 64><<<GEMM_BLOCKS, TB, 0, stream>>>(buf2, wp2, b2, buf1);
    // layer 3
    k_aggb<64><<<(N_NODES + 31) / 32, TB, 0, stream>>>(buf1, row_ptr, csr_src, dinv, buf2);
    k_gemm_mfma<64, 128><<<GEMM_BLOCKS, TB, 0, stream>>>(buf2, wp3, b3, buf1);
    // layer 4 (pool fused into epilogue)
    k_aggb<128><<<(N_NODES + 15) / 16, TB, 0, stream>>>(buf1, row_ptr, csr_src, dinv, buf2);
    k_gemm_pool<<<GEMM_BLOCKS, TB, 0, stream>>>(buf2, wp4, b4, batch, pooled);

    k_final<<<N_GRAPHS, 64, 0, stream>>>(pooled, gcount, fcW, fcb, out);
}

// Round 9
// 261.963 us; speedup vs baseline: 1.4685x; 1.1993x over previous
//
#include <hip/hip_runtime.h>
#include <hip/hip_bf16.h>
#include <math.h>

#define N_NODES 50000
#define N_EDGES 800000
#define N_GRAPHS 64
#define NUM_CLASSES 10
#define MTILES ((N_NODES + 15) / 16)          // 3125
#define BIN_W 256
#define NBINS ((N_NODES + BIN_W - 1) / BIN_W) // 196
#define CHUNK 4096
#define NCHUNKS ((N_EDGES + CHUNK - 1) / CHUNK) // 196
#define PACK_BLOCKS 21
#define INIT_BLOCKS 16

typedef __attribute__((ext_vector_type(8))) short bf16x8;
typedef __attribute__((ext_vector_type(4))) float f32x4;

__device__ inline unsigned short f2bf(float f) {
    unsigned int u = __float_as_uint(f);
    u += 0x7fffu + ((u >> 16) & 1u);
    return (unsigned short)(u >> 16);
}
__device__ inline float bf2f(unsigned short v) {
    return __uint_as_float((unsigned int)v << 16);
}
__device__ inline void bf8_unpack(uint4 v, float* o) {
    o[0] = __uint_as_float(v.x << 16); o[1] = __uint_as_float(v.x & 0xffff0000u);
    o[2] = __uint_as_float(v.y << 16); o[3] = __uint_as_float(v.y & 0xffff0000u);
    o[4] = __uint_as_float(v.z << 16); o[5] = __uint_as_float(v.z & 0xffff0000u);
    o[6] = __uint_as_float(v.w << 16); o[7] = __uint_as_float(v.w & 0xffff0000u);
}
__device__ inline unsigned int pack2(float a, float b) {
    return (unsigned int)f2bf(a) | ((unsigned int)f2bf(b) << 16);
}

// pack W (fp32 KxN row-major) into MFMA B-fragment layout, one 64-lane group per (nt,kt)
template<int K, int N>
__device__ void packW_dev(const float* __restrict__ W, unsigned short* __restrict__ Wp,
                          int bid, int l) {
    constexpr int KT = K / 32;
    int kt = bid % KT, nt = bid / KT;
    int m = l & 15, quad = l >> 4;
    #pragma unroll
    for (int j = 0; j < 8; j++) {
        int k = kt * 32 + quad * 8 + j;
        int n = nt * 16 + m;
        Wp[((size_t)bid * 64 + l) * 8 + j] = f2bf(W[(size_t)k * N + n]);
    }
}

// ---------------- k_pre: per-chunk bin histogram + weight packing + pooled init ----------------
__global__ __launch_bounds__(256) void k_pre(const int* __restrict__ dst, int* __restrict__ bin_part,
                                             const float* __restrict__ W2, const float* __restrict__ W3,
                                             const float* __restrict__ W4,
                                             unsigned short* wp2, unsigned short* wp3, unsigned short* wp4,
                                             float* pooled) {
    int bid = blockIdx.x, t = threadIdx.x;
    if (bid < NCHUNKS) {
        __shared__ int h[NBINS];
        for (int i = t; i < NBINS; i += 256) h[i] = 0;
        __syncthreads();
        int base = bid * CHUNK;
        int end = base + CHUNK; if (end > N_EDGES) end = N_EDGES;
        for (int e = base + t; e < end; e += 256)
            atomicAdd(&h[dst[e] >> 8], 1);
        __syncthreads();
        for (int i = t; i < NBINS; i += 256) bin_part[bid * NBINS + i] = h[i];
    } else if (bid < NCHUNKS + PACK_BLOCKS) {
        int w = (bid - NCHUNKS) * 4 + (t >> 6);
        int lane = t & 63;
        if (w < 4)       packW_dev<32, 64>(W2, wp2, w, lane);
        else if (w < 20) packW_dev<64, 128>(W3, wp3, w - 4, lane);
        else if (w < 84) packW_dev<128, 256>(W4, wp4, w - 20, lane);
    } else {
        int i = (bid - NCHUNKS - PACK_BLOCKS) * 1024 + t;
        #pragma unroll
        for (int q = 0; q < 4; q++) pooled[i + q * 256] = 0.0f;
    }
}

// ---------------- k_scan: bin scan (block 0) + graph counts (block 1) ----------------
__global__ __launch_bounds__(256) void k_scan(const int* __restrict__ bin_part,
                                              int* bin_start, int* bin_cursor,
                                              const int* __restrict__ batch, float* gcount) {
    int t = threadIdx.x;
    if (blockIdx.x == 0) {
        __shared__ int s[256];
        int v = 0;
        if (t < NBINS)
            for (int c = 0; c < NCHUNKS; c++) v += bin_part[c * NBINS + t];
        s[t] = v; __syncthreads();
        for (int off = 1; off < 256; off <<= 1) {
            int x = (t >= off) ? s[t - off] : 0;
            __syncthreads();
            s[t] += x;
            __syncthreads();
        }
        if (t < NBINS) { bin_start[t] = s[t] - v; bin_cursor[t] = s[t] - v; }
        if (t == 0) bin_start[NBINS] = N_EDGES;
    } else {
        int g = t;
        if (g >= N_GRAPHS) return;
        int lo = 0, hi = N_NODES;
        while (lo < hi) { int m = (lo + hi) >> 1; if (batch[m] < g) lo = m + 1; else hi = m; }
        int start = lo;
        lo = 0; hi = N_NODES;
        while (lo < hi) { int m = (lo + hi) >> 1; if (batch[m] < g + 1) lo = m + 1; else hi = m; }
        gcount[g] = (float)(lo - start);
    }
}

// ---------------- bin-scatter with LDS staging. packed = (dst&255)<<24 | src ----------------
__global__ __launch_bounds__(256) void k_binscatter(const int* __restrict__ src,
                                                    const int* __restrict__ dst,
                                                    int* bin_cursor,
                                                    unsigned int* __restrict__ binned) {
    __shared__ int hist[NBINS];
    __shared__ int off[NBINS];
    __shared__ int bump[NBINS];
    __shared__ int gbase[NBINS];
    __shared__ unsigned int stage[CHUNK];
    __shared__ unsigned char sbin[CHUNK];
    int t = threadIdx.x;
    int base = blockIdx.x * CHUNK;
    int total = N_EDGES - base; if (total > CHUNK) total = CHUNK;
    for (int i = t; i < NBINS; i += 256) { hist[i] = 0; bump[i] = 0; }
    __syncthreads();
    int es[16], ed[16];
    #pragma unroll
    for (int i = 0; i < 16; i++) {
        int e = base + t + i * 256;
        if (e < N_EDGES) { es[i] = src[e]; ed[i] = dst[e]; }
        else ed[i] = -1;
    }
    #pragma unroll
    for (int i = 0; i < 16; i++)
        if (ed[i] >= 0) atomicAdd(&hist[ed[i] >> 8], 1);
    __syncthreads();
    {
        __shared__ int s[256];
        int v = (t < NBINS) ? hist[t] : 0;
        s[t] = v; __syncthreads();
        for (int o = 1; o < 256; o <<= 1) {
            int x = (t >= o) ? s[t - o] : 0;
            __syncthreads();
            s[t] += x;
            __syncthreads();
        }
        if (t < NBINS) off[t] = s[t] - v;
    }
    __syncthreads();
    if (t < NBINS && hist[t] > 0) gbase[t] = atomicAdd(&bin_cursor[t], hist[t]);
    #pragma unroll
    for (int i = 0; i < 16; i++) {
        if (ed[i] >= 0) {
            int b = ed[i] >> 8;
            int lpos = off[b] + atomicAdd(&bump[b], 1);
            stage[lpos] = ((unsigned int)(ed[i] & 255) << 24) | (unsigned int)es[i];
            sbin[lpos] = (unsigned char)b;
        }
    }
    __syncthreads();
    for (int j = t; j < total; j += 256) {
        int b = sbin[j];
        binned[gbase[b] + (j - off[b])] = stage[j];
    }
}

// ---------------- per-bin CSR finalize ----------------
__global__ __launch_bounds__(256) void k_csr(const unsigned int* __restrict__ binned,
                                             const int* __restrict__ bin_start,
                                             int* __restrict__ row_ptr,
                                             float* __restrict__ dinv,
                                             int* __restrict__ csr_src) {
    __shared__ int deg[BIN_W];
    __shared__ int off[BIN_W];
    __shared__ int bump[BIN_W];
    int b = blockIdx.x;
    int t = threadIdx.x;
    deg[t] = 0; bump[t] = 0;
    __syncthreads();
    int e0 = bin_start[b], e1 = bin_start[b + 1];
    for (int e = e0 + t; e < e1; e += 256)
        atomicAdd(&deg[binned[e] >> 24], 1);
    __syncthreads();
    {
        __shared__ int s[256];
        int v = deg[t];
        s[t] = v; __syncthreads();
        for (int o = 1; o < 256; o <<= 1) {
            int x = (t >= o) ? s[t - o] : 0;
            __syncthreads();
            s[t] += x;
            __syncthreads();
        }
        off[t] = s[t] - v;
    }
    __syncthreads();
    int node = b * BIN_W + t;
    if (node < N_NODES) {
        row_ptr[node] = e0 + off[t];
        dinv[node] = rsqrtf((float)(deg[t] + 1));
    }
    if (b == 0 && t == 0) row_ptr[N_NODES] = N_EDGES;
    for (int e = e0 + t; e < e1; e += 256) {
        unsigned int v = binned[e];
        int dl = v >> 24;
        int pos = e0 + off[dl] + atomicAdd(&bump[dl], 1);
        csr_src[pos] = (int)(v & 0x1ffffu);
    }
}

// ---------------- aggregate (fp32 input, D=5), 8 threads/node ----------------
__global__ void k_agg5(const float* __restrict__ h, const int* __restrict__ row_ptr,
                       const int* __restrict__ csr_src,
                       const float* __restrict__ dinv, float* __restrict__ out) {
    int t = threadIdx.x;
    int f = t & 7;
    int g = t >> 3;
    int node = blockIdx.x * 32 + g;
    if (node >= N_NODES || f >= 5) return;
    float di = dinv[node];
    float acc = di * h[node * 5 + f];
    int e0 = row_ptr[node], e1 = row_ptr[node + 1];
    for (int e = e0; e < e1; e++) {
        int s = csr_src[e];
        acc += dinv[s] * h[s * 5 + f];
    }
    out[node * 5 + f] = di * acc;
}

// ---------------- aggregate, bf16 in -> bf16 out ----------------
template<int D>
__global__ void k_aggb(const unsigned short* __restrict__ h, const int* __restrict__ row_ptr,
                       const int* __restrict__ csr_src,
                       const float* __restrict__ dinv, unsigned short* __restrict__ out) {
    constexpr int DV = D / 8;
    constexpr int G = 256 / DV;
    const uint4* h4 = (const uint4*)h;
    int t = threadIdx.x;
    int f = t % DV;
    int g = t / DV;
    int node = blockIdx.x * G + g;
    if (node >= N_NODES) return;
    float di = dinv[node];
    float selfv[8];
    bf8_unpack(h4[(size_t)node * DV + f], selfv);
    float acc0[8], acc1[8];
    #pragma unroll
    for (int i = 0; i < 8; i++) { acc0[i] = di * selfv[i]; acc1[i] = 0.0f; }
    int e0 = row_ptr[node], e1 = row_ptr[node + 1];
    int e = e0;
    for (; e + 1 < e1; e += 2) {
        int s0 = csr_src[e], s1 = csr_src[e + 1];
        float w0 = dinv[s0], w1 = dinv[s1];
        uint4 u0 = h4[(size_t)s0 * DV + f];
        uint4 u1 = h4[(size_t)s1 * DV + f];
        float t0[8], t1[8];
        bf8_unpack(u0, t0);
        bf8_unpack(u1, t1);
        #pragma unroll
        for (int i = 0; i < 8; i++) { acc0[i] += w0 * t0[i]; acc1[i] += w1 * t1[i]; }
    }
    if (e < e1) {
        int s0 = csr_src[e];
        float w0 = dinv[s0];
        float t0[8];
        bf8_unpack(h4[(size_t)s0 * DV + f], t0);
        #pragma unroll
        for (int i = 0; i < 8; i++) acc0[i] += w0 * t0[i];
    }
    uint4 o;
    o.x = pack2(di * (acc0[0] + acc1[0]), di * (acc0[1] + acc1[1]));
    o.y = pack2(di * (acc0[2] + acc1[2]), di * (acc0[3] + acc1[3]));
    o.z = pack2(di * (acc0[4] + acc1[4]), di * (acc0[5] + acc1[5]));
    o.w = pack2(di * (acc0[6] + acc1[6]), di * (acc0[7] + acc1[7]));
    ((uint4*)out)[(size_t)node * DV + f] = o;
}

// ---------------- layer-1 matmul (K=5): bf16 out = relu(Hin @ W + b) ----------------
template<int DIN, int DOUT>
__global__ void k_matmul(const float* __restrict__ Hin, const float* __restrict__ W,
                         const float* __restrict__ bias, unsigned short* __restrict__ Hout) {
    constexpr int G = 256 / DOUT;
    constexpr int ROWS = 16;
    constexpr int RPB = G * ROWS;
    __shared__ float lds[RPB * DIN];
    int t = threadIdx.x;
    int row0 = blockIdx.x * RPB;
    const int base = row0 * DIN;
    const int lim = N_NODES * DIN - base;
    for (int idx = t; idx < RPB * DIN; idx += 256)
        lds[idx] = (idx < lim) ? Hin[base + idx] : 0.0f;
    __syncthreads();
    int j = t % DOUT;
    int g = t / DOUT;
    float b = bias[j];
    float acc[ROWS];
    #pragma unroll
    for (int r = 0; r < ROWS; r++) acc[r] = 0.0f;
    for (int k = 0; k < DIN; k++) {
        float w = W[k * DOUT + j];
        #pragma unroll
        for (int r = 0; r < ROWS; r++)
            acc[r] += lds[(g * ROWS + r) * DIN + k] * w;
    }
    #pragma unroll
    for (int r = 0; r < ROWS; r++) {
        int gr = row0 + g * ROWS + r;
        if (gr < N_NODES) {
            float v = acc[r] + b;
            Hout[gr * DOUT + j] = f2bf(v > 0.0f ? v : 0.0f);
        }
    }
}

// ---------------- MFMA GEMM: C = relu(A @ W + b), bf16 out ----------------
template<int K, int N>
__global__ __launch_bounds__(256) void k_gemm_mfma(const unsigned short* __restrict__ A,
                                                   const unsigned short* __restrict__ Wp,
                                                   const float* __restrict__ bias,
                                                   unsigned short* __restrict__ C) {
    constexpr int KT = K / 32, NT = N / 16;
    int wave = threadIdx.x >> 6, lane = threadIdx.x & 63;
    int wid = blockIdx.x * 4 + wave;
    int mt0 = wid * 2;
    if (mt0 >= MTILES) return;
    bool two = (mt0 + 1) < MTILES;
    int m = lane & 15, quad = lane >> 4;
    bf16x8 a0[KT], a1[KT];
    #pragma unroll
    for (int kt = 0; kt < KT; kt++) {
        a0[kt] = *(const bf16x8*)(A + (size_t)(mt0 * 16 + m) * K + kt * 32 + quad * 8);
        a1[kt] = *(const bf16x8*)(A + (size_t)((mt0 + 1) * 16 + m) * K + kt * 32 + quad * 8);
    }
    const bf16x8* Bp = (const bf16x8*)Wp;
    for (int nt = 0; nt < NT; nt++) {
        f32x4 c0 = {0.f, 0.f, 0.f, 0.f}, c1 = {0.f, 0.f, 0.f, 0.f};
        #pragma unroll
        for (int kt = 0; kt < KT; kt++) {
            bf16x8 b = Bp[(size_t)(nt * KT + kt) * 64 + lane];
            c0 = __builtin_amdgcn_mfma_f32_16x16x32_bf16(a0[kt], b, c0, 0, 0, 0);
            c1 = __builtin_amdgcn_mfma_f32_16x16x32_bf16(a1[kt], b, c1, 0, 0, 0);
        }
        int col = nt * 16 + m;
        float bv = bias[col];
        #pragma unroll
        for (int r = 0; r < 4; r++) {
            int row0 = mt0 * 16 + quad * 4 + r;
            float v0 = fmaxf(c0[r] + bv, 0.f);
            C[(size_t)row0 * N + col] = f2bf(v0);
            if (two) {
                int row1 = row0 + 16;
                float v1 = fmaxf(c1[r] + bv, 0.f);
                C[(size_t)row1 * N + col] = f2bf(v1);
            }
        }
    }
}

// ---------------- pooling (bf16 h, 256 cols), segmented accumulation ----------------
#define POOL_CHUNK 64
__global__ void k_poolb(const unsigned short* __restrict__ h, const int* __restrict__ batch,
                        float* pooled) {
    int t = threadIdx.x;                 // feature 0..255
    int n0 = blockIdx.x * POOL_CHUNK;
    int n1 = n0 + POOL_CHUNK; if (n1 > N_NODES) n1 = N_NODES;
    float acc = 0.0f;
    int cur = batch[n0];
    for (int i = n0; i < n1; i++) {
        int g = batch[i];
        if (g != cur) {
            atomicAdd(&pooled[cur * 256 + t], acc);
            acc = 0.0f; cur = g;
        }
        acc += bf2f(h[(size_t)i * 256 + t]);
    }
    atomicAdd(&pooled[cur * 256 + t], acc);
}

// ---------------- FC + log_softmax (one wave per graph) ----------------
__global__ void k_final(const float* __restrict__ pooled, const float* __restrict__ gcount,
                        const float* __restrict__ fcW, const float* __restrict__ fcb,
                        float* __restrict__ out) {
    int g = blockIdx.x;
    int t = threadIdx.x;                 // 0..63
    float p[4];
    #pragma unroll
    for (int m = 0; m < 4; m++) p[m] = pooled[g * 256 + t + 64 * m];
    float inv = 1.0f / fmaxf(gcount[g], 1.0f);
    float logits[NUM_CLASSES];
    #pragma unroll
    for (int j = 0; j < NUM_CLASSES; j++) {
        float s = 0.0f;
        #pragma unroll
        for (int m = 0; m < 4; m++) s += p[m] * fcW[(t + 64 * m) * NUM_CLASSES + j];
        for (int off = 32; off > 0; off >>= 1) s += __shfl_xor(s, off);
        logits[j] = s * inv + fcb[j];
    }
    float mx = logits[0];
    #pragma unroll
    for (int j = 1; j < NUM_CLASSES; j++) mx = fmaxf(mx, logits[j]);
    float se = 0.0f;
    #pragma unroll
    for (int j = 0; j < NUM_CLASSES; j++) se += expf(logits[j] - mx);
    float lse = mx + logf(se);
    if (t < NUM_CLASSES) out[g * NUM_CLASSES + t] = logits[t] - lse;
}

extern "C" void kernel_launch(void* const* d_in, const int* in_sizes, int n_in,
                              void* d_out, int out_size, void* d_ws, size_t ws_size,
                              hipStream_t stream) {
    const float* x     = (const float*)d_in[0];
    const int*   ei    = (const int*)d_in[1];
    const int*   src   = ei;
    const int*   dst   = ei + N_EDGES;
    const int*   batch = (const int*)d_in[2];
    const float* W1 = (const float*)d_in[3];  const float* b1 = (const float*)d_in[4];
    const float* W2 = (const float*)d_in[5];  const float* b2 = (const float*)d_in[6];
    const float* W3 = (const float*)d_in[7];  const float* b3 = (const float*)d_in[8];
    const float* W4 = (const float*)d_in[9];  const float* b4 = (const float*)d_in[10];
    const float* fcW = (const float*)d_in[11]; const float* fcb = (const float*)d_in[12];
    float* out = (float*)d_out;

    char* ws = (char*)d_ws;
    unsigned short* buf1 = (unsigned short*)ws; ws += (size_t)N_NODES * 256 * 2;
    unsigned short* buf2 = (unsigned short*)ws; ws += (size_t)N_NODES * 256 * 2;
    float* bufA     = (float*)ws; ws += (size_t)N_NODES * 8 * 4;     // agg5 out (fp32)
    float* dinv     = (float*)ws; ws += (size_t)N_NODES * 4;
    int*   row_ptr  = (int*)ws;   ws += (size_t)(N_NODES + 4) * 4;
    int*   csr_src  = (int*)ws;   ws += (size_t)N_EDGES * 4;
    unsigned int* binned = (unsigned int*)ws; ws += (size_t)N_EDGES * 4;
    int*   bin_part = (int*)ws;   ws += (size_t)NCHUNKS * NBINS * 4;
    int*   bin_start= (int*)ws;   ws += (NBINS + 4) * 4;
    int*   bin_cur  = (int*)ws;   ws += (NBINS + 4) * 4;
    float* pooled   = (float*)ws; ws += (size_t)N_GRAPHS * 256 * 4;
    float* gcount   = (float*)ws; ws += 256 * 4;
    unsigned short* wp2 = (unsigned short*)ws; ws += 32 * 64 * 2;
    unsigned short* wp3 = (unsigned short*)ws; ws += 64 * 128 * 2;
    unsigned short* wp4 = (unsigned short*)ws; ws += 128 * 256 * 2;

    const int TB = 256;
    const int GEMM_BLOCKS = ((MTILES + 1) / 2 + 3) / 4;   // 391

    k_pre<<<NCHUNKS + PACK_BLOCKS + INIT_BLOCKS, TB, 0, stream>>>(dst, bin_part, W2, W3, W4,
                                                                  wp2, wp3, wp4, pooled);
    k_scan<<<2, TB, 0, stream>>>(bin_part, bin_start, bin_cur, batch, gcount);
    k_binscatter<<<NCHUNKS, TB, 0, stream>>>(src, dst, bin_cur, binned);
    k_csr<<<NBINS, TB, 0, stream>>>(binned, bin_start, row_ptr, dinv, csr_src);

    // layer 1: agg(x)[5] -> mm 5->32 (bf16 out)
    k_agg5<<<(N_NODES + 31) / 32, TB, 0, stream>>>(x, row_ptr, csr_src, dinv, bufA);
    k_matmul<5, 32><<<(N_NODES + 127) / 128, TB, 0, stream>>>(bufA, W1, b1, buf1);
    // layer 2
    k_aggb<32><<<(N_NODES + 63) / 64, TB, 0, stream>>>(buf1, row_ptr, csr_src, dinv, buf2);
    k_gemm_mfma<32, 64><<<GEMM_BLOCKS, TB, 0, stream>>>(buf2, wp2, b2, buf1);
    // layer 3
    k_aggb<64><<<(N_NODES + 31) / 32, TB, 0, stream>>>(buf1, row_ptr, csr_src, dinv, buf2);
    k_gemm_mfma<64, 128><<<GEMM_BLOCKS, TB, 0, stream>>>(buf2, wp3, b3, buf1);
    // layer 4
    k_aggb<128><<<(N_NODES + 15) / 16, TB, 0, stream>>>(buf1, row_ptr, csr_src, dinv, buf2);
    k_gemm_mfma<128, 256><<<GEMM_BLOCKS, TB, 0, stream>>>(buf2, wp4, b4, buf1);

    // pooling + classifier
    k_poolb<<<(N_NODES + POOL_CHUNK - 1) / POOL_CHUNK, TB, 0, stream>>>(buf1, batch, pooled);
    k_final<<<N_GRAPHS, 64, 0, stream>>>(pooled, gcount, fcW, fcb, out);
}

// Round 10
// 238.414 us; speedup vs baseline: 1.6135x; 1.0988x over previous
//
#include <hip/hip_runtime.h>
#include <hip/hip_bf16.h>
#include <math.h>

#define N_NODES 50000
#define N_EDGES 800000
#define N_GRAPHS 64
#define NUM_CLASSES 10
#define BIN_W 256
#define NBINS ((N_NODES + BIN_W - 1) / BIN_W) // 196
#define CHUNK 4096
#define NCHUNKS ((N_EDGES + CHUNK - 1) / CHUNK) // 196
#define PACK_BLOCKS 21
#define INIT_BLOCKS 16

typedef __attribute__((ext_vector_type(8))) short bf16x8;
typedef __attribute__((ext_vector_type(4))) float f32x4;

__device__ inline unsigned short f2bf(float f) {
    unsigned int u = __float_as_uint(f);
    u += 0x7fffu + ((u >> 16) & 1u);
    return (unsigned short)(u >> 16);
}
__device__ inline float bf2f(unsigned short v) {
    return __uint_as_float((unsigned int)v << 16);
}
__device__ inline void bf8_unpack(uint4 v, float* o) {
    o[0] = __uint_as_float(v.x << 16); o[1] = __uint_as_float(v.x & 0xffff0000u);
    o[2] = __uint_as_float(v.y << 16); o[3] = __uint_as_float(v.y & 0xffff0000u);
    o[4] = __uint_as_float(v.z << 16); o[5] = __uint_as_float(v.z & 0xffff0000u);
    o[6] = __uint_as_float(v.w << 16); o[7] = __uint_as_float(v.w & 0xffff0000u);
}
__device__ inline unsigned int pack2(float a, float b) {
    return (unsigned int)f2bf(a) | ((unsigned int)f2bf(b) << 16);
}

// pack W (fp32 KxN row-major) into MFMA B-fragment layout, one 64-lane group per (nt,kt)
template<int K, int N>
__device__ void packW_dev(const float* __restrict__ W, unsigned short* __restrict__ Wp,
                          int bid, int l) {
    constexpr int KT = K / 32;
    int kt = bid % KT, nt = bid / KT;
    int m = l & 15, quad = l >> 4;
    #pragma unroll
    for (int j = 0; j < 8; j++) {
        int k = kt * 32 + quad * 8 + j;
        int n = nt * 16 + m;
        Wp[((size_t)bid * 64 + l) * 8 + j] = f2bf(W[(size_t)k * N + n]);
    }
}

// ---------------- k_pre: per-chunk bin histogram + weight packing + pooled init ----------------
__global__ __launch_bounds__(256) void k_pre(const int* __restrict__ dst, int* __restrict__ bin_part,
                                             const float* __restrict__ W2, const float* __restrict__ W3,
                                             const float* __restrict__ W4,
                                             unsigned short* wp2, unsigned short* wp3, unsigned short* wp4,
                                             float* pooled) {
    int bid = blockIdx.x, t = threadIdx.x;
    if (bid < NCHUNKS) {
        __shared__ int h[NBINS];
        for (int i = t; i < NBINS; i += 256) h[i] = 0;
        __syncthreads();
        int base = bid * CHUNK;
        int end = base + CHUNK; if (end > N_EDGES) end = N_EDGES;
        for (int e = base + t; e < end; e += 256)
            atomicAdd(&h[dst[e] >> 8], 1);
        __syncthreads();
        for (int i = t; i < NBINS; i += 256) bin_part[bid * NBINS + i] = h[i];
    } else if (bid < NCHUNKS + PACK_BLOCKS) {
        int w = (bid - NCHUNKS) * 4 + (t >> 6);
        int lane = t & 63;
        if (w < 4)       packW_dev<32, 64>(W2, wp2, w, lane);
        else if (w < 20) packW_dev<64, 128>(W3, wp3, w - 4, lane);
        else if (w < 84) packW_dev<128, 256>(W4, wp4, w - 20, lane);
    } else {
        int i = (bid - NCHUNKS - PACK_BLOCKS) * 1024 + t;
        #pragma unroll
        for (int q = 0; q < 4; q++) pooled[i + q * 256] = 0.0f;
    }
}

// ---------------- k_scan: bin scan (block 0) + graph counts (block 1) ----------------
__global__ __launch_bounds__(256) void k_scan(const int* __restrict__ bin_part,
                                              int* bin_start, int* bin_cursor,
                                              const int* __restrict__ batch, float* gcount) {
    int t = threadIdx.x;
    if (blockIdx.x == 0) {
        __shared__ int s[256];
        int v = 0;
        if (t < NBINS)
            for (int c = 0; c < NCHUNKS; c++) v += bin_part[c * NBINS + t];
        s[t] = v; __syncthreads();
        for (int off = 1; off < 256; off <<= 1) {
            int x = (t >= off) ? s[t - off] : 0;
            __syncthreads();
            s[t] += x;
            __syncthreads();
        }
        if (t < NBINS) { bin_start[t] = s[t] - v; bin_cursor[t] = s[t] - v; }
        if (t == 0) bin_start[NBINS] = N_EDGES;
    } else {
        int g = t;
        if (g >= N_GRAPHS) return;
        int lo = 0, hi = N_NODES;
        while (lo < hi) { int m = (lo + hi) >> 1; if (batch[m] < g) lo = m + 1; else hi = m; }
        int start = lo;
        lo = 0; hi = N_NODES;
        while (lo < hi) { int m = (lo + hi) >> 1; if (batch[m] < g + 1) lo = m + 1; else hi = m; }
        gcount[g] = (float)(lo - start);
    }
}

// ---------------- bin-scatter with LDS staging. packed = (dst&255)<<16 | src (src<65536) ----------------
__global__ __launch_bounds__(256) void k_binscatter(const int* __restrict__ src,
                                                    const int* __restrict__ dst,
                                                    int* bin_cursor,
                                                    unsigned int* __restrict__ binned) {
    __shared__ int hist[NBINS];
    __shared__ int off[NBINS];
    __shared__ int bump[NBINS];
    __shared__ int gbase[NBINS];
    __shared__ unsigned int stage[CHUNK];
    __shared__ unsigned char sbin[CHUNK];
    int t = threadIdx.x;
    int base = blockIdx.x * CHUNK;
    int total = N_EDGES - base; if (total > CHUNK) total = CHUNK;
    for (int i = t; i < NBINS; i += 256) { hist[i] = 0; bump[i] = 0; }
    __syncthreads();
    int es[16], ed[16];
    #pragma unroll
    for (int i = 0; i < 16; i++) {
        int e = base + t + i * 256;
        if (e < N_EDGES) { es[i] = src[e]; ed[i] = dst[e]; }
        else ed[i] = -1;
    }
    #pragma unroll
    for (int i = 0; i < 16; i++)
        if (ed[i] >= 0) atomicAdd(&hist[ed[i] >> 8], 1);
    __syncthreads();
    {
        __shared__ int s[256];
        int v = (t < NBINS) ? hist[t] : 0;
        s[t] = v; __syncthreads();
        for (int o = 1; o < 256; o <<= 1) {
            int x = (t >= o) ? s[t - o] : 0;
            __syncthreads();
            s[t] += x;
            __syncthreads();
        }
        if (t < NBINS) off[t] = s[t] - v;
    }
    __syncthreads();
    if (t < NBINS && hist[t] > 0) gbase[t] = atomicAdd(&bin_cursor[t], hist[t]);
    #pragma unroll
    for (int i = 0; i < 16; i++) {
        if (ed[i] >= 0) {
            int b = ed[i] >> 8;
            int lpos = off[b] + atomicAdd(&bump[b], 1);
            stage[lpos] = ((unsigned int)(ed[i] & 255) << 16) | (unsigned int)es[i];
            sbin[lpos] = (unsigned char)b;
        }
    }
    __syncthreads();
    for (int j = t; j < total; j += 256) {
        int b = sbin[j];
        binned[gbase[b] + (j - off[b])] = stage[j];
    }
}

// ---------------- per-bin CSR finalize (csr_src as ushort) ----------------
__global__ __launch_bounds__(256) void k_csr(const unsigned int* __restrict__ binned,
                                             const int* __restrict__ bin_start,
                                             int* __restrict__ row_ptr,
                                             float* __restrict__ dinv,
                                             unsigned short* __restrict__ csr16) {
    __shared__ int deg[BIN_W];
    __shared__ int off[BIN_W];
    __shared__ int bump[BIN_W];
    int b = blockIdx.x;
    int t = threadIdx.x;
    deg[t] = 0; bump[t] = 0;
    __syncthreads();
    int e0 = bin_start[b], e1 = bin_start[b + 1];
    for (int e = e0 + t; e < e1; e += 256)
        atomicAdd(&deg[binned[e] >> 16], 1);
    __syncthreads();
    {
        __shared__ int s[256];
        int v = deg[t];
        s[t] = v; __syncthreads();
        for (int o = 1; o < 256; o <<= 1) {
            int x = (t >= o) ? s[t - o] : 0;
            __syncthreads();
            s[t] += x;
            __syncthreads();
        }
        off[t] = s[t] - v;
    }
    __syncthreads();
    int node = b * BIN_W + t;
    if (node < N_NODES) {
        row_ptr[node] = e0 + off[t];
        dinv[node] = rsqrtf((float)(deg[t] + 1));
    }
    if (b == 0 && t == 0) row_ptr[N_NODES] = N_EDGES;
    for (int e = e0 + t; e < e1; e += 256) {
        unsigned int v = binned[e];
        int dl = v >> 16;
        int pos = e0 + off[dl] + atomicAdd(&bump[dl], 1);
        csr16[pos] = (unsigned short)(v & 0xffffu);
    }
}

// ---------------- layer 1 fused: agg5 + matmul 5->32 (32 nodes/block, 1563 blocks) ----------------
__global__ __launch_bounds__(256) void k_layer1(const float* __restrict__ x,
                                                const int* __restrict__ row_ptr,
                                                const unsigned short* __restrict__ csr16,
                                                const float* __restrict__ dinv,
                                                const float* __restrict__ W1,
                                                const float* __restrict__ b1,
                                                unsigned short* __restrict__ Hout) {
    __shared__ float A5[32 * 6];
    __shared__ float Ws[160];
    __shared__ float bs[32];
    int t = threadIdx.x;
    int row0 = blockIdx.x * 32;
    if (t < 160) Ws[t] = W1[t];
    if (t >= 224) bs[t - 224] = b1[t - 224];
    int nl = t >> 3, f = t & 7;
    int node = row0 + nl;
    float val = 0.0f;
    if (f < 5 && node < N_NODES) {
        float di = dinv[node];
        float acc = di * x[node * 5 + f];
        int e0 = row_ptr[node], e1 = row_ptr[node + 1];
        for (int e = e0; e < e1; e++) {
            int s = csr16[e];
            acc += dinv[s] * x[s * 5 + f];
        }
        val = di * acc;
    }
    if (f < 5) A5[nl * 6 + f] = val;
    __syncthreads();
    int j0 = (t & 7) * 4;
    float a[5];
    #pragma unroll
    for (int k = 0; k < 5; k++) a[k] = A5[(t >> 3) * 6 + k];
    ushort4 o;
    unsigned short* op = (unsigned short*)&o;
    #pragma unroll
    for (int c = 0; c < 4; c++) {
        float acc = bs[j0 + c];
        #pragma unroll
        for (int k = 0; k < 5; k++) acc += a[k] * Ws[k * 32 + j0 + c];
        op[c] = f2bf(fmaxf(acc, 0.0f));
    }
    if (node < N_NODES) *(ushort4*)&Hout[(size_t)node * 32 + j0] = o;
}

// ---------------- fused layer: gather-aggregate (LDS) + MFMA GEMM, NPB=2048/K nodes/block ----------------
template<int K, int N>
__global__ __launch_bounds__(256) void k_fused(const unsigned short* __restrict__ Hin,
                                               const int* __restrict__ row_ptr,
                                               const unsigned short* __restrict__ csr16,
                                               const float* __restrict__ dinv,
                                               const unsigned short* __restrict__ Wp,
                                               const float* __restrict__ bias,
                                               unsigned short* __restrict__ C) {
    constexpr int KT = K / 32, NT = N / 16, DV = K / 8;
    constexpr int NPB = 2048 / K;     // nodes per block (64/32/16)
    constexpr int TM = NPB / 16;      // M-tiles per block (4/2/1)
    constexpr int KP = K + 8;         // padded row (bf16 units), keeps 16B align
    __shared__ unsigned short As[NPB * KP];
    int t = threadIdx.x;
    int row0 = blockIdx.x * NPB;
    // ---- phase 1: aggregate NPB nodes into LDS ----
    {
        int nl = t / DV, f = t % DV;
        int node = row0 + nl;
        const uint4* h4 = (const uint4*)Hin;
        uint4 o = {0u, 0u, 0u, 0u};
        if (node < N_NODES) {
            float di = dinv[node];
            float selfv[8];
            bf8_unpack(h4[(size_t)node * DV + f], selfv);
            float acc0[8], acc1[8];
            #pragma unroll
            for (int i = 0; i < 8; i++) { acc0[i] = di * selfv[i]; acc1[i] = 0.0f; }
            int e0 = row_ptr[node], e1 = row_ptr[node + 1];
            int e = e0;
            for (; e + 1 < e1; e += 2) {
                int s0 = csr16[e], s1 = csr16[e + 1];
                float w0 = dinv[s0], w1 = dinv[s1];
                uint4 u0 = h4[(size_t)s0 * DV + f];
                uint4 u1 = h4[(size_t)s1 * DV + f];
                float t0[8], t1[8];
                bf8_unpack(u0, t0);
                bf8_unpack(u1, t1);
                #pragma unroll
                for (int i = 0; i < 8; i++) { acc0[i] += w0 * t0[i]; acc1[i] += w1 * t1[i]; }
            }
            if (e < e1) {
                int s0 = csr16[e];
                float w0 = dinv[s0];
                float t0[8];
                bf8_unpack(h4[(size_t)s0 * DV + f], t0);
                #pragma unroll
                for (int i = 0; i < 8; i++) acc0[i] += w0 * t0[i];
            }
            o.x = pack2(di * (acc0[0] + acc1[0]), di * (acc0[1] + acc1[1]));
            o.y = pack2(di * (acc0[2] + acc1[2]), di * (acc0[3] + acc1[3]));
            o.z = pack2(di * (acc0[4] + acc1[4]), di * (acc0[5] + acc1[5]));
            o.w = pack2(di * (acc0[6] + acc1[6]), di * (acc0[7] + acc1[7]));
        }
        *(uint4*)&As[nl * KP + f * 8] = o;
    }
    __syncthreads();
    // ---- phase 2: MFMA, 4 waves job-split over TM x NT tiles ----
    int wave = t >> 6, lane = t & 63;
    int m = lane & 15, quad = lane >> 4;
    bf16x8 a[TM][KT];
    #pragma unroll
    for (int mt = 0; mt < TM; mt++)
        #pragma unroll
        for (int kt = 0; kt < KT; kt++)
            a[mt][kt] = *(const bf16x8*)&As[(mt * 16 + m) * KP + kt * 32 + quad * 8];
    const bf16x8* Bp = (const bf16x8*)Wp;
    for (int j = wave; j < TM * NT; j += 4) {
        int mt = j % TM, nt = j / TM;
        f32x4 c = {0.f, 0.f, 0.f, 0.f};
        #pragma unroll
        for (int kt = 0; kt < KT; kt++)
            c = __builtin_amdgcn_mfma_f32_16x16x32_bf16(a[mt][kt],
                    Bp[(size_t)(nt * KT + kt) * 64 + lane], c, 0, 0, 0);
        int col = nt * 16 + m;
        float bv = bias[col];
        #pragma unroll
        for (int r = 0; r < 4; r++) {
            int row = row0 + mt * 16 + quad * 4 + r;
            if (row < N_NODES)
                C[(size_t)row * N + col] = f2bf(fmaxf(c[r] + bv, 0.0f));
        }
    }
}

// ---------------- pooling (bf16 h, 256 cols), segmented accumulation ----------------
#define POOL_CHUNK 64
__global__ void k_poolb(const unsigned short* __restrict__ h, const int* __restrict__ batch,
                        float* pooled) {
    int t = threadIdx.x;                 // feature 0..255
    int n0 = blockIdx.x * POOL_CHUNK;
    int n1 = n0 + POOL_CHUNK; if (n1 > N_NODES) n1 = N_NODES;
    float acc = 0.0f;
    int cur = batch[n0];
    for (int i = n0; i < n1; i++) {
        int g = batch[i];
        if (g != cur) {
            atomicAdd(&pooled[cur * 256 + t], acc);
            acc = 0.0f; cur = g;
        }
        acc += bf2f(h[(size_t)i * 256 + t]);
    }
    atomicAdd(&pooled[cur * 256 + t], acc);
}

// ---------------- FC + log_softmax (one wave per graph) ----------------
__global__ void k_final(const float* __restrict__ pooled, const float* __restrict__ gcount,
                        const float* __restrict__ fcW, const float* __restrict__ fcb,
                        float* __restrict__ out) {
    int g = blockIdx.x;
    int t = threadIdx.x;                 // 0..63
    float p[4];
    #pragma unroll
    for (int m = 0; m < 4; m++) p[m] = pooled[g * 256 + t + 64 * m];
    float inv = 1.0f / fmaxf(gcount[g], 1.0f);
    float logits[NUM_CLASSES];
    #pragma unroll
    for (int j = 0; j < NUM_CLASSES; j++) {
        float s = 0.0f;
        #pragma unroll
        for (int m = 0; m < 4; m++) s += p[m] * fcW[(t + 64 * m) * NUM_CLASSES + j];
        for (int off = 32; off > 0; off >>= 1) s += __shfl_xor(s, off);
        logits[j] = s * inv + fcb[j];
    }
    float mx = logits[0];
    #pragma unroll
    for (int j = 1; j < NUM_CLASSES; j++) mx = fmaxf(mx, logits[j]);
    float se = 0.0f;
    #pragma unroll
    for (int j = 0; j < NUM_CLASSES; j++) se += expf(logits[j] - mx);
    float lse = mx + logf(se);
    if (t < NUM_CLASSES) out[g * NUM_CLASSES + t] = logits[t] - lse;
}

extern "C" void kernel_launch(void* const* d_in, const int* in_sizes, int n_in,
                              void* d_out, int out_size, void* d_ws, size_t ws_size,
                              hipStream_t stream) {
    const float* x     = (const float*)d_in[0];
    const int*   ei    = (const int*)d_in[1];
    const int*   src   = ei;
    const int*   dst   = ei + N_EDGES;
    const int*   batch = (const int*)d_in[2];
    const float* W1 = (const float*)d_in[3];  const float* b1 = (const float*)d_in[4];
    const float* W2 = (const float*)d_in[5];  const float* b2 = (const float*)d_in[6];
    const float* W3 = (const float*)d_in[7];  const float* b3 = (const float*)d_in[8];
    const float* W4 = (const float*)d_in[9];  const float* b4 = (const float*)d_in[10];
    const float* fcW = (const float*)d_in[11]; const float* fcb = (const float*)d_in[12];
    float* out = (float*)d_out;

    char* ws = (char*)d_ws;
    unsigned short* buf1 = (unsigned short*)ws; ws += (size_t)N_NODES * 256 * 2;
    unsigned short* buf2 = (unsigned short*)ws; ws += (size_t)N_NODES * 256 * 2;
    float* dinv     = (float*)ws; ws += (size_t)N_NODES * 4;
    int*   row_ptr  = (int*)ws;   ws += (size_t)(N_NODES + 4) * 4;
    unsigned short* csr16 = (unsigned short*)ws; ws += (size_t)N_EDGES * 2;
    unsigned int* binned = (unsigned int*)ws; ws += (size_t)N_EDGES * 4;
    int*   bin_part = (int*)ws;   ws += (size_t)NCHUNKS * NBINS * 4;
    int*   bin_start= (int*)ws;   ws += (NBINS + 4) * 4;
    int*   bin_cur  = (int*)ws;   ws += (NBINS + 4) * 4;
    float* pooled   = (float*)ws; ws += (size_t)N_GRAPHS * 256 * 4;
    float* gcount   = (float*)ws; ws += 256 * 4;
    unsigned short* wp2 = (unsigned short*)ws; ws += 32 * 64 * 2;
    unsigned short* wp3 = (unsigned short*)ws; ws += 64 * 128 * 2;
    unsigned short* wp4 = (unsigned short*)ws; ws += 128 * 256 * 2;

    const int TB = 256;
    k_pre<<<NCHUNKS + PACK_BLOCKS + INIT_BLOCKS, TB, 0, stream>>>(dst, bin_part, W2, W3, W4,
                                                                  wp2, wp3, wp4, pooled);
    k_scan<<<2, TB, 0, stream>>>(bin_part, bin_start, bin_cur, batch, gcount);
    k_binscatter<<<NCHUNKS, TB, 0, stream>>>(src, dst, bin_cur, binned);
    k_csr<<<NBINS, TB, 0, stream>>>(binned, bin_start, row_ptr, dinv, csr16);

    // layer 1: fused agg5 + 5->32 matmul
    k_layer1<<<(N_NODES + 31) / 32, TB, 0, stream>>>(x, row_ptr, csr16, dinv, W1, b1, buf1);
    // layers 2-4: fused aggregate + MFMA GEMM
    k_fused<32, 64><<<(N_NODES + 63) / 64, TB, 0, stream>>>(buf1, row_ptr, csr16, dinv, wp2, b2, buf2);
    k_fused<64, 128><<<(N_NODES + 31) / 32, TB, 0, stream>>>(buf2, row_ptr, csr16, dinv, wp3, b3, buf1);
    k_fused<128, 256><<<(N_NODES + 15) / 16, TB, 0, stream>>>(buf1, row_ptr, csr16, dinv, wp4, b4, buf2);

    // pooling + classifier
    k_poolb<<<(N_NODES + POOL_CHUNK - 1) / POOL_CHUNK, TB, 0, stream>>>(buf2, batch, pooled);
    k_final<<<N_GRAPHS, 64, 0, stream>>>(pooled, gcount, fcW, fcb, out);
}

// Round 11
// 230.445 us; speedup vs baseline: 1.6693x; 1.0346x over previous
//
#include <hip/hip_runtime.h>
#include <hip/hip_bf16.h>
#include <math.h>

#define N_NODES 50000
#define N_EDGES 800000
#define N_GRAPHS 64
#define NUM_CLASSES 10
#define BIN_W 256
#define NBINS ((N_NODES + BIN_W - 1) / BIN_W) // 196
#define CHUNK 4096
#define NCHUNKS ((N_EDGES + CHUNK - 1) / CHUNK) // 196
#define CAP 8192                               // per-bin edge capacity (mean 4082, >60 sigma)
#define PACK_BLOCKS 21
#define INIT_BLOCKS 16

typedef __attribute__((ext_vector_type(8))) short bf16x8;
typedef __attribute__((ext_vector_type(4))) float f32x4;

__device__ inline unsigned short f2bf(float f) {
    unsigned int u = __float_as_uint(f);
    u += 0x7fffu + ((u >> 16) & 1u);
    return (unsigned short)(u >> 16);
}
__device__ inline float bf2f(unsigned short v) {
    return __uint_as_float((unsigned int)v << 16);
}
__device__ inline void bf8_unpack(uint4 v, float* o) {
    o[0] = __uint_as_float(v.x << 16); o[1] = __uint_as_float(v.x & 0xffff0000u);
    o[2] = __uint_as_float(v.y << 16); o[3] = __uint_as_float(v.y & 0xffff0000u);
    o[4] = __uint_as_float(v.z << 16); o[5] = __uint_as_float(v.z & 0xffff0000u);
    o[6] = __uint_as_float(v.w << 16); o[7] = __uint_as_float(v.w & 0xffff0000u);
}
__device__ inline unsigned int pack2(float a, float b) {
    return (unsigned int)f2bf(a) | ((unsigned int)f2bf(b) << 16);
}

// pack W (fp32 KxN row-major) into MFMA B-fragment layout, one 64-lane group per (nt,kt)
template<int K, int N>
__device__ void packW_dev(const float* __restrict__ W, unsigned short* __restrict__ Wp,
                          int bid, int l) {
    constexpr int KT = K / 32;
    int kt = bid % KT, nt = bid / KT;
    int m = l & 15, quad = l >> 4;
    #pragma unroll
    for (int j = 0; j < 8; j++) {
        int k = kt * 32 + quad * 8 + j;
        int n = nt * 16 + m;
        Wp[((size_t)bid * 64 + l) * 8 + j] = f2bf(W[(size_t)k * N + n]);
    }
}

// ---------------- k_pre: weight packing + pooled/bin_cnt init ----------------
__global__ __launch_bounds__(256) void k_pre(const float* __restrict__ W2, const float* __restrict__ W3,
                                             const float* __restrict__ W4,
                                             unsigned short* wp2, unsigned short* wp3, unsigned short* wp4,
                                             float* pooled, int* bin_cnt) {
    int bid = blockIdx.x, t = threadIdx.x;
    if (bid < PACK_BLOCKS) {
        int w = bid * 4 + (t >> 6);
        int lane = t & 63;
        if (w < 4)       packW_dev<32, 64>(W2, wp2, w, lane);
        else if (w < 20) packW_dev<64, 128>(W3, wp3, w - 4, lane);
        else if (w < 84) packW_dev<128, 256>(W4, wp4, w - 20, lane);
    } else if (bid < PACK_BLOCKS + INIT_BLOCKS) {
        int i = (bid - PACK_BLOCKS) * 1024 + t;
        #pragma unroll
        for (int q = 0; q < 4; q++) pooled[i + q * 256] = 0.0f;
    } else {
        if (t < NBINS) bin_cnt[t] = 0;
    }
}

// ---------------- bin-scatter with LDS staging, fixed-capacity bins ----------------
// packed = (dst&255)<<16 | src  (src < 65536)
__global__ __launch_bounds__(256) void k_binscatter(const int* __restrict__ src,
                                                    const int* __restrict__ dst,
                                                    int* bin_cnt,
                                                    unsigned int* __restrict__ binned) {
    __shared__ int hist[NBINS];
    __shared__ int off[NBINS];
    __shared__ int bump[NBINS];
    __shared__ int gbase[NBINS];
    __shared__ unsigned int stage[CHUNK];
    __shared__ unsigned char sbin[CHUNK];
    int t = threadIdx.x;
    int base = blockIdx.x * CHUNK;
    int total = N_EDGES - base; if (total > CHUNK) total = CHUNK;
    for (int i = t; i < NBINS; i += 256) { hist[i] = 0; bump[i] = 0; }
    __syncthreads();
    int es[16], ed[16];
    #pragma unroll
    for (int i = 0; i < 16; i++) {
        int e = base + t + i * 256;
        if (e < N_EDGES) { es[i] = src[e]; ed[i] = dst[e]; }
        else ed[i] = -1;
    }
    #pragma unroll
    for (int i = 0; i < 16; i++)
        if (ed[i] >= 0) atomicAdd(&hist[ed[i] >> 8], 1);
    __syncthreads();
    {
        __shared__ int s[256];
        int v = (t < NBINS) ? hist[t] : 0;
        s[t] = v; __syncthreads();
        for (int o = 1; o < 256; o <<= 1) {
            int x = (t >= o) ? s[t - o] : 0;
            __syncthreads();
            s[t] += x;
            __syncthreads();
        }
        if (t < NBINS) off[t] = s[t] - v;
    }
    __syncthreads();
    if (t < NBINS && hist[t] > 0)
        gbase[t] = t * CAP + atomicAdd(&bin_cnt[t], hist[t]);
    #pragma unroll
    for (int i = 0; i < 16; i++) {
        if (ed[i] >= 0) {
            int b = ed[i] >> 8;
            int lpos = off[b] + atomicAdd(&bump[b], 1);
            stage[lpos] = ((unsigned int)(ed[i] & 255) << 16) | (unsigned int)es[i];
            sbin[lpos] = (unsigned char)b;
        }
    }
    __syncthreads();
    for (int j = t; j < total; j += 256) {
        int b = sbin[j];
        binned[gbase[b] + (j - off[b])] = stage[j];
    }
}

// ---------------- per-bin CSR finalize: row_ptr packed (start | deg<<21), csr_src ushort ----------------
__global__ __launch_bounds__(256) void k_csr(const unsigned int* __restrict__ binned,
                                             const int* __restrict__ bin_cnt,
                                             unsigned int* __restrict__ row_ptr,
                                             float* __restrict__ dinv,
                                             unsigned short* __restrict__ csr16) {
    __shared__ int deg[BIN_W];
    __shared__ int off[BIN_W];
    __shared__ int bump[BIN_W];
    int b = blockIdx.x;
    int t = threadIdx.x;
    deg[t] = 0; bump[t] = 0;
    __syncthreads();
    int e0 = b * CAP;
    int e1 = e0 + bin_cnt[b];
    for (int e = e0 + t; e < e1; e += 256)
        atomicAdd(&deg[binned[e] >> 16], 1);
    __syncthreads();
    {
        __shared__ int s[256];
        int v = deg[t];
        s[t] = v; __syncthreads();
        for (int o = 1; o < 256; o <<= 1) {
            int x = (t >= o) ? s[t - o] : 0;
            __syncthreads();
            s[t] += x;
            __syncthreads();
        }
        off[t] = s[t] - v;
    }
    __syncthreads();
    int node = b * BIN_W + t;
    if (node < N_NODES) {
        row_ptr[node] = (unsigned int)(e0 + off[t]) | ((unsigned int)deg[t] << 21);
        dinv[node] = rsqrtf((float)(deg[t] + 1));
    }
    for (int e = e0 + t; e < e1; e += 256) {
        unsigned int v = binned[e];
        int dl = v >> 16;
        int pos = e0 + off[dl] + atomicAdd(&bump[dl], 1);
        csr16[pos] = (unsigned short)(v & 0xffffu);
    }
}

// ---------------- layer 1 fused: agg5 + matmul 5->32 (32 nodes/block, 1563 blocks) ----------------
__global__ __launch_bounds__(256) void k_layer1(const float* __restrict__ x,
                                                const unsigned int* __restrict__ row_ptr,
                                                const unsigned short* __restrict__ csr16,
                                                const float* __restrict__ dinv,
                                                const float* __restrict__ W1,
                                                const float* __restrict__ b1,
                                                unsigned short* __restrict__ Hout) {
    __shared__ float A5[32 * 6];
    __shared__ float Ws[160];
    __shared__ float bs[32];
    int t = threadIdx.x;
    int row0 = blockIdx.x * 32;
    if (t < 160) Ws[t] = W1[t];
    if (t >= 224) bs[t - 224] = b1[t - 224];
    int nl = t >> 3, f = t & 7;
    int node = row0 + nl;
    float val = 0.0f;
    if (f < 5 && node < N_NODES) {
        float di = dinv[node];
        float acc = di * x[node * 5 + f];
        unsigned int v = row_ptr[node];
        int e0 = (int)(v & 0x1FFFFFu);
        int e1 = e0 + (int)(v >> 21);
        for (int e = e0; e < e1; e++) {
            int s = csr16[e];
            acc += dinv[s] * x[s * 5 + f];
        }
        val = di * acc;
    }
    if (f < 5) A5[nl * 6 + f] = val;
    __syncthreads();
    int j0 = (t & 7) * 4;
    float a[5];
    #pragma unroll
    for (int k = 0; k < 5; k++) a[k] = A5[(t >> 3) * 6 + k];
    ushort4 o;
    unsigned short* op = (unsigned short*)&o;
    #pragma unroll
    for (int c = 0; c < 4; c++) {
        float acc = bs[j0 + c];
        #pragma unroll
        for (int k = 0; k < 5; k++) acc += a[k] * Ws[k * 32 + j0 + c];
        op[c] = f2bf(fmaxf(acc, 0.0f));
    }
    if (node < N_NODES) *(ushort4*)&Hout[(size_t)node * 32 + j0] = o;
}

// ---------------- fused layer: gather-aggregate (LDS) + MFMA GEMM, NPB=2048/K nodes/block ----------------
template<int K, int N>
__global__ __launch_bounds__(256) void k_fused(const unsigned short* __restrict__ Hin,
                                               const unsigned int* __restrict__ row_ptr,
                                               const unsigned short* __restrict__ csr16,
                                               const float* __restrict__ dinv,
                                               const unsigned short* __restrict__ Wp,
                                               const float* __restrict__ bias,
                                               unsigned short* __restrict__ C) {
    constexpr int KT = K / 32, NT = N / 16, DV = K / 8;
    constexpr int NPB = 2048 / K;     // nodes per block (64/32/16)
    constexpr int TM = NPB / 16;      // M-tiles per block (4/2/1)
    constexpr int KP = K + 8;         // padded row (bf16 units), keeps 16B align
    __shared__ unsigned short As[NPB * KP];
    int t = threadIdx.x;
    int row0 = blockIdx.x * NPB;
    // ---- phase 1: aggregate NPB nodes into LDS ----
    {
        int nl = t / DV, f = t % DV;
        int node = row0 + nl;
        const uint4* h4 = (const uint4*)Hin;
        uint4 o = {0u, 0u, 0u, 0u};
        if (node < N_NODES) {
            float di = dinv[node];
            float selfv[8];
            bf8_unpack(h4[(size_t)node * DV + f], selfv);
            float acc0[8], acc1[8];
            #pragma unroll
            for (int i = 0; i < 8; i++) { acc0[i] = di * selfv[i]; acc1[i] = 0.0f; }
            unsigned int rv = row_ptr[node];
            int e0 = (int)(rv & 0x1FFFFFu);
            int e1 = e0 + (int)(rv >> 21);
            int e = e0;
            for (; e + 1 < e1; e += 2) {
                int s0 = csr16[e], s1 = csr16[e + 1];
                float w0 = dinv[s0], w1 = dinv[s1];
                uint4 u0 = h4[(size_t)s0 * DV + f];
                uint4 u1 = h4[(size_t)s1 * DV + f];
                float t0[8], t1[8];
                bf8_unpack(u0, t0);
                bf8_unpack(u1, t1);
                #pragma unroll
                for (int i = 0; i < 8; i++) { acc0[i] += w0 * t0[i]; acc1[i] += w1 * t1[i]; }
            }
            if (e < e1) {
                int s0 = csr16[e];
                float w0 = dinv[s0];
                float t0[8];
                bf8_unpack(h4[(size_t)s0 * DV + f], t0);
                #pragma unroll
                for (int i = 0; i < 8; i++) acc0[i] += w0 * t0[i];
            }
            o.x = pack2(di * (acc0[0] + acc1[0]), di * (acc0[1] + acc1[1]));
            o.y = pack2(di * (acc0[2] + acc1[2]), di * (acc0[3] + acc1[3]));
            o.z = pack2(di * (acc0[4] + acc1[4]), di * (acc0[5] + acc1[5]));
            o.w = pack2(di * (acc0[6] + acc1[6]), di * (acc0[7] + acc1[7]));
        }
        *(uint4*)&As[nl * KP + f * 8] = o;
    }
    __syncthreads();
    // ---- phase 2: MFMA, 4 waves job-split over TM x NT tiles ----
    int wave = t >> 6, lane = t & 63;
    int m = lane & 15, quad = lane >> 4;
    bf16x8 a[TM][KT];
    #pragma unroll
    for (int mt = 0; mt < TM; mt++)
        #pragma unroll
        for (int kt = 0; kt < KT; kt++)
            a[mt][kt] = *(const bf16x8*)&As[(mt * 16 + m) * KP + kt * 32 + quad * 8];
    const bf16x8* Bp = (const bf16x8*)Wp;
    for (int j = wave; j < TM * NT; j += 4) {
        int mt = j % TM, nt = j / TM;
        f32x4 c = {0.f, 0.f, 0.f, 0.f};
        #pragma unroll
        for (int kt = 0; kt < KT; kt++)
            c = __builtin_amdgcn_mfma_f32_16x16x32_bf16(a[mt][kt],
                    Bp[(size_t)(nt * KT + kt) * 64 + lane], c, 0, 0, 0);
        int col = nt * 16 + m;
        float bv = bias[col];
        #pragma unroll
        for (int r = 0; r < 4; r++) {
            int row = row0 + mt * 16 + quad * 4 + r;
            if (row < N_NODES)
                C[(size_t)row * N + col] = f2bf(fmaxf(c[r] + bv, 0.0f));
        }
    }
}

// ---------------- pooling (bf16 h, 256 cols), segmented accumulation ----------------
#define POOL_CHUNK 64
__global__ void k_poolb(const unsigned short* __restrict__ h, const int* __restrict__ batch,
                        float* pooled) {
    int t = threadIdx.x;                 // feature 0..255
    int n0 = blockIdx.x * POOL_CHUNK;
    int n1 = n0 + POOL_CHUNK; if (n1 > N_NODES) n1 = N_NODES;
    float acc = 0.0f;
    int cur = batch[n0];
    for (int i = n0; i < n1; i++) {
        int g = batch[i];
        if (g != cur) {
            atomicAdd(&pooled[cur * 256 + t], acc);
            acc = 0.0f; cur = g;
        }
        acc += bf2f(h[(size_t)i * 256 + t]);
    }
    atomicAdd(&pooled[cur * 256 + t], acc);
}

// ---------------- FC + log_softmax (one wave per graph; count via binary search) ----------------
__global__ void k_final(const float* __restrict__ pooled, const int* __restrict__ batch,
                        const float* __restrict__ fcW, const float* __restrict__ fcb,
                        float* __restrict__ out) {
    int g = blockIdx.x;
    int t = threadIdx.x;                 // 0..63
    float cnt = 0.0f;
    if (t == 0) {
        int lo = 0, hi = N_NODES;
        while (lo < hi) { int m = (lo + hi) >> 1; if (batch[m] < g) lo = m + 1; else hi = m; }
        int start = lo;
        lo = 0; hi = N_NODES;
        while (lo < hi) { int m = (lo + hi) >> 1; if (batch[m] < g + 1) lo = m + 1; else hi = m; }
        cnt = (float)(lo - start);
    }
    float inv = 1.0f / fmaxf(__shfl(cnt, 0), 1.0f);
    float p[4];
    #pragma unroll
    for (int m = 0; m < 4; m++) p[m] = pooled[g * 256 + t + 64 * m];
    float logits[NUM_CLASSES];
    #pragma unroll
    for (int j = 0; j < NUM_CLASSES; j++) {
        float s = 0.0f;
        #pragma unroll
        for (int m = 0; m < 4; m++) s += p[m] * fcW[(t + 64 * m) * NUM_CLASSES + j];
        for (int off = 32; off > 0; off >>= 1) s += __shfl_xor(s, off);
        logits[j] = s * inv + fcb[j];
    }
    float mx = logits[0];
    #pragma unroll
    for (int j = 1; j < NUM_CLASSES; j++) mx = fmaxf(mx, logits[j]);
    float se = 0.0f;
    #pragma unroll
    for (int j = 0; j < NUM_CLASSES; j++) se += expf(logits[j] - mx);
    float lse = mx + logf(se);
    if (t < NUM_CLASSES) out[g * NUM_CLASSES + t] = logits[t] - lse;
}

extern "C" void kernel_launch(void* const* d_in, const int* in_sizes, int n_in,
                              void* d_out, int out_size, void* d_ws, size_t ws_size,
                              hipStream_t stream) {
    const float* x     = (const float*)d_in[0];
    const int*   ei    = (const int*)d_in[1];
    const int*   src   = ei;
    const int*   dst   = ei + N_EDGES;
    const int*   batch = (const int*)d_in[2];
    const float* W1 = (const float*)d_in[3];  const float* b1 = (const float*)d_in[4];
    const float* W2 = (const float*)d_in[5];  const float* b2 = (const float*)d_in[6];
    const float* W3 = (const float*)d_in[7];  const float* b3 = (const float*)d_in[8];
    const float* W4 = (const float*)d_in[9];  const float* b4 = (const float*)d_in[10];
    const float* fcW = (const float*)d_in[11]; const float* fcb = (const float*)d_in[12];
    float* out = (float*)d_out;

    char* ws = (char*)d_ws;
    unsigned short* buf1 = (unsigned short*)ws; ws += (size_t)N_NODES * 256 * 2;
    unsigned short* buf2 = (unsigned short*)ws; ws += (size_t)N_NODES * 256 * 2;
    float* dinv     = (float*)ws; ws += (size_t)N_NODES * 4;
    unsigned int* row_ptr = (unsigned int*)ws; ws += (size_t)(N_NODES + 4) * 4;
    unsigned short* csr16 = (unsigned short*)ws; ws += (size_t)NBINS * CAP * 2;
    unsigned int* binned = (unsigned int*)ws; ws += (size_t)NBINS * CAP * 4;
    int*   bin_cnt  = (int*)ws;   ws += (NBINS + 4) * 4;
    float* pooled   = (float*)ws; ws += (size_t)N_GRAPHS * 256 * 4;
    unsigned short* wp2 = (unsigned short*)ws; ws += 32 * 64 * 2;
    unsigned short* wp3 = (unsigned short*)ws; ws += 64 * 128 * 2;
    unsigned short* wp4 = (unsigned short*)ws; ws += 128 * 256 * 2;

    const int TB = 256;
    k_pre<<<PACK_BLOCKS + INIT_BLOCKS + 1, TB, 0, stream>>>(W2, W3, W4, wp2, wp3, wp4,
                                                            pooled, bin_cnt);
    k_binscatter<<<NCHUNKS, TB, 0, stream>>>(src, dst, bin_cnt, binned);
    k_csr<<<NBINS, TB, 0, stream>>>(binned, bin_cnt, row_ptr, dinv, csr16);

    // layer 1: fused agg5 + 5->32 matmul
    k_layer1<<<(N_NODES + 31) / 32, TB, 0, stream>>>(x, row_ptr, csr16, dinv, W1, b1, buf1);
    // layers 2-4: fused aggregate + MFMA GEMM
    k_fused<32, 64><<<(N_NODES + 63) / 64, TB, 0, stream>>>(buf1, row_ptr, csr16, dinv, wp2, b2, buf2);
    k_fused<64, 128><<<(N_NODES + 31) / 32, TB, 0, stream>>>(buf2, row_ptr, csr16, dinv, wp3, b3, buf1);
    k_fused<128, 256><<<(N_NODES + 15) / 16, TB, 0, stream>>>(buf1, row_ptr, csr16, dinv, wp4, b4, buf2);

    // pooling + classifier
    k_poolb<<<(N_NODES + POOL_CHUNK - 1) / POOL_CHUNK, TB, 0, stream>>>(buf2, batch, pooled);
    k_final<<<N_GRAPHS, 64, 0, stream>>>(pooled, batch, fcW, fcb, out);
}

// Round 12
// 221.587 us; speedup vs baseline: 1.7361x; 1.0400x over previous
//
#include <hip/hip_runtime.h>
#include <hip/hip_bf16.h>
#include <math.h>

#define N_NODES 50000
#define N_EDGES 800000
#define N_GRAPHS 64
#define NUM_CLASSES 10
#define BIN_W 256
#define NBINS ((N_NODES + BIN_W - 1) / BIN_W) // 196
#define CHUNK 4096
#define NCHUNKS ((N_EDGES + CHUNK - 1) / CHUNK) // 196
#define CAP 8192                               // per-bin edge capacity (mean 4082, >60 sigma)
#define PACK_BLOCKS 21
#define INIT_BLOCKS 16

typedef __attribute__((ext_vector_type(8))) short bf16x8;
typedef __attribute__((ext_vector_type(4))) float f32x4;

__device__ inline unsigned short f2bf(float f) {
    unsigned int u = __float_as_uint(f);
    u += 0x7fffu + ((u >> 16) & 1u);
    return (unsigned short)(u >> 16);
}
__device__ inline float bf2f(unsigned short v) {
    return __uint_as_float((unsigned int)v << 16);
}
__device__ inline void bf8_unpack(uint4 v, float* o) {
    o[0] = __uint_as_float(v.x << 16); o[1] = __uint_as_float(v.x & 0xffff0000u);
    o[2] = __uint_as_float(v.y << 16); o[3] = __uint_as_float(v.y & 0xffff0000u);
    o[4] = __uint_as_float(v.z << 16); o[5] = __uint_as_float(v.z & 0xffff0000u);
    o[6] = __uint_as_float(v.w << 16); o[7] = __uint_as_float(v.w & 0xffff0000u);
}
__device__ inline unsigned int pack2(float a, float b) {
    return (unsigned int)f2bf(a) | ((unsigned int)f2bf(b) << 16);
}

// pack W (fp32 KxN row-major) into MFMA B-fragment layout, one 64-lane group per (nt,kt)
template<int K, int N>
__device__ void packW_dev(const float* __restrict__ W, unsigned short* __restrict__ Wp,
                          int bid, int l) {
    constexpr int KT = K / 32;
    int kt = bid % KT, nt = bid / KT;
    int m = l & 15, quad = l >> 4;
    #pragma unroll
    for (int j = 0; j < 8; j++) {
        int k = kt * 32 + quad * 8 + j;
        int n = nt * 16 + m;
        Wp[((size_t)bid * 64 + l) * 8 + j] = f2bf(W[(size_t)k * N + n]);
    }
}

// ---------------- k_pre: weight packing + pooled/bin_cnt init ----------------
__global__ __launch_bounds__(256) void k_pre(const float* __restrict__ W2, const float* __restrict__ W3,
                                             const float* __restrict__ W4,
                                             unsigned short* wp2, unsigned short* wp3, unsigned short* wp4,
                                             float* pooled, int* bin_cnt) {
    int bid = blockIdx.x, t = threadIdx.x;
    if (bid < PACK_BLOCKS) {
        int w = bid * 4 + (t >> 6);
        int lane = t & 63;
        if (w < 4)       packW_dev<32, 64>(W2, wp2, w, lane);
        else if (w < 20) packW_dev<64, 128>(W3, wp3, w - 4, lane);
        else if (w < 84) packW_dev<128, 256>(W4, wp4, w - 20, lane);
    } else if (bid < PACK_BLOCKS + INIT_BLOCKS) {
        int i = (bid - PACK_BLOCKS) * 1024 + t;
        #pragma unroll
        for (int q = 0; q < 4; q++) pooled[i + q * 256] = 0.0f;
    } else {
        if (t < NBINS) bin_cnt[t] = 0;
    }
}

// ---------------- bin-scatter with LDS staging, fixed-capacity bins ----------------
// packed = (dst&255)<<16 | src  (src < 65536)
__global__ __launch_bounds__(256) void k_binscatter(const int* __restrict__ src,
                                                    const int* __restrict__ dst,
                                                    int* bin_cnt,
                                                    unsigned int* __restrict__ binned) {
    __shared__ int hist[NBINS];
    __shared__ int off[NBINS];
    __shared__ int bump[NBINS];
    __shared__ int gbase[NBINS];
    __shared__ unsigned int stage[CHUNK];
    __shared__ unsigned char sbin[CHUNK];
    int t = threadIdx.x;
    int base = blockIdx.x * CHUNK;
    int total = N_EDGES - base; if (total > CHUNK) total = CHUNK;
    for (int i = t; i < NBINS; i += 256) { hist[i] = 0; bump[i] = 0; }
    __syncthreads();
    int es[16], ed[16];
    #pragma unroll
    for (int i = 0; i < 16; i++) {
        int e = base + t + i * 256;
        if (e < N_EDGES) { es[i] = src[e]; ed[i] = dst[e]; }
        else ed[i] = -1;
    }
    #pragma unroll
    for (int i = 0; i < 16; i++)
        if (ed[i] >= 0) atomicAdd(&hist[ed[i] >> 8], 1);
    __syncthreads();
    {
        __shared__ int s[256];
        int v = (t < NBINS) ? hist[t] : 0;
        s[t] = v; __syncthreads();
        for (int o = 1; o < 256; o <<= 1) {
            int x = (t >= o) ? s[t - o] : 0;
            __syncthreads();
            s[t] += x;
            __syncthreads();
        }
        if (t < NBINS) off[t] = s[t] - v;
    }
    __syncthreads();
    if (t < NBINS && hist[t] > 0)
        gbase[t] = t * CAP + atomicAdd(&bin_cnt[t], hist[t]);
    #pragma unroll
    for (int i = 0; i < 16; i++) {
        if (ed[i] >= 0) {
            int b = ed[i] >> 8;
            int lpos = off[b] + atomicAdd(&bump[b], 1);
            stage[lpos] = ((unsigned int)(ed[i] & 255) << 16) | (unsigned int)es[i];
            sbin[lpos] = (unsigned char)b;
        }
    }
    __syncthreads();
    for (int j = t; j < total; j += 256) {
        int b = sbin[j];
        binned[gbase[b] + (j - off[b])] = stage[j];
    }
}

// ---------------- per-bin CSR finalize: row_ptr packed (start | deg<<21), csr_src ushort ----------------
__global__ __launch_bounds__(256) void k_csr(const unsigned int* __restrict__ binned,
                                             const int* __restrict__ bin_cnt,
                                             unsigned int* __restrict__ row_ptr,
                                             float* __restrict__ dinv,
                                             unsigned short* __restrict__ csr16) {
    __shared__ int deg[BIN_W];
    __shared__ int off[BIN_W];
    __shared__ int bump[BIN_W];
    int b = blockIdx.x;
    int t = threadIdx.x;
    deg[t] = 0; bump[t] = 0;
    __syncthreads();
    int e0 = b * CAP;
    int e1 = e0 + bin_cnt[b];
    for (int e = e0 + t; e < e1; e += 256)
        atomicAdd(&deg[binned[e] >> 16], 1);
    __syncthreads();
    {
        __shared__ int s[256];
        int v = deg[t];
        s[t] = v; __syncthreads();
        for (int o = 1; o < 256; o <<= 1) {
            int x = (t >= o) ? s[t - o] : 0;
            __syncthreads();
            s[t] += x;
            __syncthreads();
        }
        off[t] = s[t] - v;
    }
    __syncthreads();
    int node = b * BIN_W + t;
    if (node < N_NODES) {
        row_ptr[node] = (unsigned int)(e0 + off[t]) | ((unsigned int)deg[t] << 21);
        dinv[node] = rsqrtf((float)(deg[t] + 1));
    }
    for (int e = e0 + t; e < e1; e += 256) {
        unsigned int v = binned[e];
        int dl = v >> 16;
        int pos = e0 + off[dl] + atomicAdd(&bump[dl], 1);
        csr16[pos] = (unsigned short)(v & 0xffffu);
    }
}

// ---------------- layer 1 fused: agg5 + matmul 5->32 (32 nodes/block, 1563 blocks) ----------------
__global__ __launch_bounds__(256) void k_layer1(const float* __restrict__ x,
                                                const unsigned int* __restrict__ row_ptr,
                                                const unsigned short* __restrict__ csr16,
                                                const float* __restrict__ dinv,
                                                const float* __restrict__ W1,
                                                const float* __restrict__ b1,
                                                unsigned short* __restrict__ Hout) {
    __shared__ float A5[32 * 6];
    __shared__ float Ws[160];
    __shared__ float bs[32];
    int t = threadIdx.x;
    int row0 = blockIdx.x * 32;
    if (t < 160) Ws[t] = W1[t];
    if (t >= 224) bs[t - 224] = b1[t - 224];
    int nl = t >> 3, f = t & 7;
    int node = row0 + nl;
    float val = 0.0f;
    if (f < 5 && node < N_NODES) {
        float di = dinv[node];
        float acc0 = di * x[node * 5 + f], acc1 = 0.0f;
        unsigned int v = row_ptr[node];
        int e0 = (int)(v & 0x1FFFFFu);
        int e1 = e0 + (int)(v >> 21);
        int e = e0;
        for (; e + 3 < e1; e += 4) {
            int s0 = csr16[e], s1 = csr16[e + 1], s2 = csr16[e + 2], s3 = csr16[e + 3];
            float w0 = dinv[s0], w1 = dinv[s1], w2 = dinv[s2], w3 = dinv[s3];
            float x0 = x[s0 * 5 + f], x1 = x[s1 * 5 + f];
            float x2 = x[s2 * 5 + f], x3 = x[s3 * 5 + f];
            acc0 += w0 * x0 + w2 * x2;
            acc1 += w1 * x1 + w3 * x3;
        }
        for (; e < e1; e++) {
            int s = csr16[e];
            acc0 += dinv[s] * x[s * 5 + f];
        }
        val = di * (acc0 + acc1);
    }
    if (f < 5) A5[nl * 6 + f] = val;
    __syncthreads();
    int j0 = (t & 7) * 4;
    float a[5];
    #pragma unroll
    for (int k = 0; k < 5; k++) a[k] = A5[(t >> 3) * 6 + k];
    ushort4 o;
    unsigned short* op = (unsigned short*)&o;
    #pragma unroll
    for (int c = 0; c < 4; c++) {
        float acc = bs[j0 + c];
        #pragma unroll
        for (int k = 0; k < 5; k++) acc += a[k] * Ws[k * 32 + j0 + c];
        op[c] = f2bf(fmaxf(acc, 0.0f));
    }
    if (node < N_NODES) *(ushort4*)&Hout[(size_t)node * 32 + j0] = o;
}

// ---------------- fused layer: gather-aggregate (LDS) + MFMA GEMM, NPB=2048/K nodes/block ----------------
template<int K, int N>
__global__ __launch_bounds__(256) void k_fused(const unsigned short* __restrict__ Hin,
                                               const unsigned int* __restrict__ row_ptr,
                                               const unsigned short* __restrict__ csr16,
                                               const float* __restrict__ dinv,
                                               const unsigned short* __restrict__ Wp,
                                               const float* __restrict__ bias,
                                               unsigned short* __restrict__ C) {
    constexpr int KT = K / 32, NT = N / 16, DV = K / 8;
    constexpr int NPB = 2048 / K;     // nodes per block (64/32/16)
    constexpr int TM = NPB / 16;      // M-tiles per block (4/2/1)
    constexpr int KP = K + 8;         // padded row (bf16 units), keeps 16B align
    __shared__ unsigned short As[NPB * KP];
    int t = threadIdx.x;
    int row0 = blockIdx.x * NPB;
    // ---- phase 1: aggregate NPB nodes into LDS (4-deep load pipeline) ----
    {
        int nl = t / DV, f = t % DV;
        int node = row0 + nl;
        const uint4* h4 = (const uint4*)Hin;
        uint4 o = {0u, 0u, 0u, 0u};
        if (node < N_NODES) {
            float di = dinv[node];
            float selfv[8];
            bf8_unpack(h4[(size_t)node * DV + f], selfv);
            float acc0[8], acc1[8];
            #pragma unroll
            for (int i = 0; i < 8; i++) { acc0[i] = di * selfv[i]; acc1[i] = 0.0f; }
            unsigned int rv = row_ptr[node];
            int e0 = (int)(rv & 0x1FFFFFu);
            int e1 = e0 + (int)(rv >> 21);
            int e = e0;
            for (; e + 3 < e1; e += 4) {
                int s0 = csr16[e], s1 = csr16[e + 1], s2 = csr16[e + 2], s3 = csr16[e + 3];
                float w0 = dinv[s0], w1 = dinv[s1], w2 = dinv[s2], w3 = dinv[s3];
                uint4 u0 = h4[(size_t)s0 * DV + f];
                uint4 u1 = h4[(size_t)s1 * DV + f];
                uint4 u2 = h4[(size_t)s2 * DV + f];
                uint4 u3 = h4[(size_t)s3 * DV + f];
                float t0[8], t1[8], t2[8], t3[8];
                bf8_unpack(u0, t0);
                bf8_unpack(u1, t1);
                bf8_unpack(u2, t2);
                bf8_unpack(u3, t3);
                #pragma unroll
                for (int i = 0; i < 8; i++) {
                    acc0[i] += w0 * t0[i] + w2 * t2[i];
                    acc1[i] += w1 * t1[i] + w3 * t3[i];
                }
            }
            for (; e + 1 < e1; e += 2) {
                int s0 = csr16[e], s1 = csr16[e + 1];
                float w0 = dinv[s0], w1 = dinv[s1];
                uint4 u0 = h4[(size_t)s0 * DV + f];
                uint4 u1 = h4[(size_t)s1 * DV + f];
                float t0[8], t1[8];
                bf8_unpack(u0, t0);
                bf8_unpack(u1, t1);
                #pragma unroll
                for (int i = 0; i < 8; i++) { acc0[i] += w0 * t0[i]; acc1[i] += w1 * t1[i]; }
            }
            if (e < e1) {
                int s0 = csr16[e];
                float w0 = dinv[s0];
                float t0[8];
                bf8_unpack(h4[(size_t)s0 * DV + f], t0);
                #pragma unroll
                for (int i = 0; i < 8; i++) acc0[i] += w0 * t0[i];
            }
            o.x = pack2(di * (acc0[0] + acc1[0]), di * (acc0[1] + acc1[1]));
            o.y = pack2(di * (acc0[2] + acc1[2]), di * (acc0[3] + acc1[3]));
            o.z = pack2(di * (acc0[4] + acc1[4]), di * (acc0[5] + acc1[5]));
            o.w = pack2(di * (acc0[6] + acc1[6]), di * (acc0[7] + acc1[7]));
        }
        *(uint4*)&As[nl * KP + f * 8] = o;
    }
    __syncthreads();
    // ---- phase 2: MFMA, 4 waves job-split over TM x NT tiles ----
    int wave = t >> 6, lane = t & 63;
    int m = lane & 15, quad = lane >> 4;
    bf16x8 a[TM][KT];
    #pragma unroll
    for (int mt = 0; mt < TM; mt++)
        #pragma unroll
        for (int kt = 0; kt < KT; kt++)
            a[mt][kt] = *(const bf16x8*)&As[(mt * 16 + m) * KP + kt * 32 + quad * 8];
    const bf16x8* Bp = (const bf16x8*)Wp;
    for (int j = wave; j < TM * NT; j += 4) {
        int mt = j % TM, nt = j / TM;
        f32x4 c = {0.f, 0.f, 0.f, 0.f};
        #pragma unroll
        for (int kt = 0; kt < KT; kt++)
            c = __builtin_amdgcn_mfma_f32_16x16x32_bf16(a[mt][kt],
                    Bp[(size_t)(nt * KT + kt) * 64 + lane], c, 0, 0, 0);
        int col = nt * 16 + m;
        float bv = bias[col];
        #pragma unroll
        for (int r = 0; r < 4; r++) {
            int row = row0 + mt * 16 + quad * 4 + r;
            if (row < N_NODES)
                C[(size_t)row * N + col] = f2bf(fmaxf(c[r] + bv, 0.0f));
        }
    }
}

// ---------------- pooling (bf16 h, 256 cols), segmented accumulation, 4-row fast path ----------------
#define POOL_CHUNK 64
__global__ void k_poolb(const unsigned short* __restrict__ h, const int* __restrict__ batch,
                        float* pooled) {
    int t = threadIdx.x;                 // feature 0..255
    int n0 = blockIdx.x * POOL_CHUNK;
    int n1 = n0 + POOL_CHUNK; if (n1 > N_NODES) n1 = N_NODES;
    float acc = 0.0f;
    int cur = batch[n0];
    int i = n0;
    while (i + 3 < n1) {
        int g0 = batch[i], g3 = batch[i + 3];
        if (g0 == cur && g3 == cur) {      // fast path: 4 rows, same graph
            float v0 = bf2f(h[(size_t)i * 256 + t]);
            float v1 = bf2f(h[(size_t)(i + 1) * 256 + t]);
            float v2 = bf2f(h[(size_t)(i + 2) * 256 + t]);
            float v3 = bf2f(h[(size_t)(i + 3) * 256 + t]);
            acc += (v0 + v1) + (v2 + v3);
            i += 4;
        } else {
            if (g0 != cur) {
                atomicAdd(&pooled[cur * 256 + t], acc);
                acc = 0.0f; cur = g0;
            }
            acc += bf2f(h[(size_t)i * 256 + t]);
            i++;
        }
    }
    for (; i < n1; i++) {
        int g = batch[i];
        if (g != cur) {
            atomicAdd(&pooled[cur * 256 + t], acc);
            acc = 0.0f; cur = g;
        }
        acc += bf2f(h[(size_t)i * 256 + t]);
    }
    atomicAdd(&pooled[cur * 256 + t], acc);
}

// ---------------- FC + log_softmax (one wave per graph; count via binary search) ----------------
__global__ void k_final(const float* __restrict__ pooled, const int* __restrict__ batch,
                        const float* __restrict__ fcW, const float* __restrict__ fcb,
                        float* __restrict__ out) {
    int g = blockIdx.x;
    int t = threadIdx.x;                 // 0..63
    float cnt = 0.0f;
    if (t == 0) {
        int lo = 0, hi = N_NODES;
        while (lo < hi) { int m = (lo + hi) >> 1; if (batch[m] < g) lo = m + 1; else hi = m; }
        int start = lo;
        lo = 0; hi = N_NODES;
        while (lo < hi) { int m = (lo + hi) >> 1; if (batch[m] < g + 1) lo = m + 1; else hi = m; }
        cnt = (float)(lo - start);
    }
    float inv = 1.0f / fmaxf(__shfl(cnt, 0), 1.0f);
    float p[4];
    #pragma unroll
    for (int m = 0; m < 4; m++) p[m] = pooled[g * 256 + t + 64 * m];
    float logits[NUM_CLASSES];
    #pragma unroll
    for (int j = 0; j < NUM_CLASSES; j++) {
        float s = 0.0f;
        #pragma unroll
        for (int m = 0; m < 4; m++) s += p[m] * fcW[(t + 64 * m) * NUM_CLASSES + j];
        for (int off = 32; off > 0; off >>= 1) s += __shfl_xor(s, off);
        logits[j] = s * inv + fcb[j];
    }
    float mx = logits[0];
    #pragma unroll
    for (int j = 1; j < NUM_CLASSES; j++) mx = fmaxf(mx, logits[j]);
    float se = 0.0f;
    #pragma unroll
    for (int j = 0; j < NUM_CLASSES; j++) se += expf(logits[j] - mx);
    float lse = mx + logf(se);
    if (t < NUM_CLASSES) out[g * NUM_CLASSES + t] = logits[t] - lse;
}

extern "C" void kernel_launch(void* const* d_in, const int* in_sizes, int n_in,
                              void* d_out, int out_size, void* d_ws, size_t ws_size,
                              hipStream_t stream) {
    const float* x     = (const float*)d_in[0];
    const int*   ei    = (const int*)d_in[1];
    const int*   src   = ei;
    const int*   dst   = ei + N_EDGES;
    const int*   batch = (const int*)d_in[2];
    const float* W1 = (const float*)d_in[3];  const float* b1 = (const float*)d_in[4];
    const float* W2 = (const float*)d_in[5];  const float* b2 = (const float*)d_in[6];
    const float* W3 = (const float*)d_in[7];  const float* b3 = (const float*)d_in[8];
    const float* W4 = (const float*)d_in[9];  const float* b4 = (const float*)d_in[10];
    const float* fcW = (const float*)d_in[11]; const float* fcb = (const float*)d_in[12];
    float* out = (float*)d_out;

    char* ws = (char*)d_ws;
    unsigned short* buf1 = (unsigned short*)ws; ws += (size_t)N_NODES * 256 * 2;
    unsigned short* buf2 = (unsigned short*)ws; ws += (size_t)N_NODES * 256 * 2;
    float* dinv     = (float*)ws; ws += (size_t)N_NODES * 4;
    unsigned int* row_ptr = (unsigned int*)ws; ws += (size_t)(N_NODES + 4) * 4;
    unsigned short* csr16 = (unsigned short*)ws; ws += (size_t)NBINS * CAP * 2;
    unsigned int* binned = (unsigned int*)ws; ws += (size_t)NBINS * CAP * 4;
    int*   bin_cnt  = (int*)ws;   ws += (NBINS + 4) * 4;
    float* pooled   = (float*)ws; ws += (size_t)N_GRAPHS * 256 * 4;
    unsigned short* wp2 = (unsigned short*)ws; ws += 32 * 64 * 2;
    unsigned short* wp3 = (unsigned short*)ws; ws += 64 * 128 * 2;
    unsigned short* wp4 = (unsigned short*)ws; ws += 128 * 256 * 2;

    const int TB = 256;
    k_pre<<<PACK_BLOCKS + INIT_BLOCKS + 1, TB, 0, stream>>>(W2, W3, W4, wp2, wp3, wp4,
                                                            pooled, bin_cnt);
    k_binscatter<<<NCHUNKS, TB, 0, stream>>>(src, dst, bin_cnt, binned);
    k_csr<<<NBINS, TB, 0, stream>>>(binned, bin_cnt, row_ptr, dinv, csr16);

    // layer 1: fused agg5 + 5->32 matmul
    k_layer1<<<(N_NODES + 31) / 32, TB, 0, stream>>>(x, row_ptr, csr16, dinv, W1, b1, buf1);
    // layers 2-4: fused aggregate + MFMA GEMM
    k_fused<32, 64><<<(N_NODES + 63) / 64, TB, 0, stream>>>(buf1, row_ptr, csr16, dinv, wp2, b2, buf2);
    k_fused<64, 128><<<(N_NODES + 31) / 32, TB, 0, stream>>>(buf2, row_ptr, csr16, dinv, wp3, b3, buf1);
    k_fused<128, 256><<<(N_NODES + 15) / 16, TB, 0, stream>>>(buf1, row_ptr, csr16, dinv, wp4, b4, buf2);

    // pooling + classifier
    k_poolb<<<(N_NODES + POOL_CHUNK - 1) / POOL_CHUNK, TB, 0, stream>>>(buf2, batch, pooled);
    k_final<<<N_GRAPHS, 64, 0, stream>>>(pooled, batch, fcW, fcb, out);
}

// Round 13
// 209.508 us; speedup vs baseline: 1.8362x; 1.0577x over previous
//
#include <hip/hip_runtime.h>
#include <hip/hip_bf16.h>
#include <math.h>

#define N_NODES 50000
#define N_EDGES 800000
#define N_GRAPHS 64
#define NUM_CLASSES 10
#define BIN_W 256
#define NBINS ((N_NODES + BIN_W - 1) / BIN_W) // 196
#define CHUNK 4096
#define NCHUNKS ((N_EDGES + CHUNK - 1) / CHUNK) // 196
#define CAP 8192                               // per-bin edge capacity (mean 4082, >60 sigma)
#define PACK_BLOCKS 21
#define INIT_BLOCKS 16

typedef __attribute__((ext_vector_type(8))) short bf16x8;
typedef __attribute__((ext_vector_type(4))) float f32x4;

__device__ inline unsigned short f2bf(float f) {
    unsigned int u = __float_as_uint(f);
    u += 0x7fffu + ((u >> 16) & 1u);
    return (unsigned short)(u >> 16);
}
__device__ inline float bf2f(unsigned short v) {
    return __uint_as_float((unsigned int)v << 16);
}
__device__ inline void bf8_unpack(uint4 v, float* o) {
    o[0] = __uint_as_float(v.x << 16); o[1] = __uint_as_float(v.x & 0xffff0000u);
    o[2] = __uint_as_float(v.y << 16); o[3] = __uint_as_float(v.y & 0xffff0000u);
    o[4] = __uint_as_float(v.z << 16); o[5] = __uint_as_float(v.z & 0xffff0000u);
    o[6] = __uint_as_float(v.w << 16); o[7] = __uint_as_float(v.w & 0xffff0000u);
}
__device__ inline unsigned int pack2(float a, float b) {
    return (unsigned int)f2bf(a) | ((unsigned int)f2bf(b) << 16);
}

// pack W (fp32 KxN row-major) into MFMA B-fragment layout, one 64-lane group per (nt,kt)
template<int K, int N>
__device__ void packW_dev(const float* __restrict__ W, unsigned short* __restrict__ Wp,
                          int bid, int l) {
    constexpr int KT = K / 32;
    int kt = bid % KT, nt = bid / KT;
    int m = l & 15, quad = l >> 4;
    #pragma unroll
    for (int j = 0; j < 8; j++) {
        int k = kt * 32 + quad * 8 + j;
        int n = nt * 16 + m;
        Wp[((size_t)bid * 64 + l) * 8 + j] = f2bf(W[(size_t)k * N + n]);
    }
}

// ---------------- k_pre: weight packing + pooled/bin_cnt init ----------------
__global__ __launch_bounds__(256) void k_pre(const float* __restrict__ W2, const float* __restrict__ W3,
                                             const float* __restrict__ W4,
                                             unsigned short* wp2, unsigned short* wp3, unsigned short* wp4,
                                             float* pooled, int* bin_cnt) {
    int bid = blockIdx.x, t = threadIdx.x;
    if (bid < PACK_BLOCKS) {
        int w = bid * 4 + (t >> 6);
        int lane = t & 63;
        if (w < 4)       packW_dev<32, 64>(W2, wp2, w, lane);
        else if (w < 20) packW_dev<64, 128>(W3, wp3, w - 4, lane);
        else if (w < 84) packW_dev<128, 256>(W4, wp4, w - 20, lane);
    } else if (bid < PACK_BLOCKS + INIT_BLOCKS) {
        int i = (bid - PACK_BLOCKS) * 1024 + t;
        #pragma unroll
        for (int q = 0; q < 4; q++) pooled[i + q * 256] = 0.0f;
    } else {
        if (t < NBINS) bin_cnt[t] = 0;
    }
}

// ---------------- bin-scatter with LDS staging, fixed-capacity bins ----------------
// packed = (dst&255)<<16 | src  (src < 65536)
__global__ __launch_bounds__(256) void k_binscatter(const int* __restrict__ src,
                                                    const int* __restrict__ dst,
                                                    int* bin_cnt,
                                                    unsigned int* __restrict__ binned) {
    __shared__ int hist[NBINS];
    __shared__ int off[NBINS];
    __shared__ int bump[NBINS];
    __shared__ int gbase[NBINS];
    __shared__ unsigned int stage[CHUNK];
    __shared__ unsigned char sbin[CHUNK];
    int t = threadIdx.x;
    int base = blockIdx.x * CHUNK;
    int total = N_EDGES - base; if (total > CHUNK) total = CHUNK;
    for (int i = t; i < NBINS; i += 256) { hist[i] = 0; bump[i] = 0; }
    __syncthreads();
    int es[16], ed[16];
    #pragma unroll
    for (int i = 0; i < 16; i++) {
        int e = base + t + i * 256;
        if (e < N_EDGES) { es[i] = src[e]; ed[i] = dst[e]; }
        else ed[i] = -1;
    }
    #pragma unroll
    for (int i = 0; i < 16; i++)
        if (ed[i] >= 0) atomicAdd(&hist[ed[i] >> 8], 1);
    __syncthreads();
    {
        __shared__ int s[256];
        int v = (t < NBINS) ? hist[t] : 0;
        s[t] = v; __syncthreads();
        for (int o = 1; o < 256; o <<= 1) {
            int x = (t >= o) ? s[t - o] : 0;
            __syncthreads();
            s[t] += x;
            __syncthreads();
        }
        if (t < NBINS) off[t] = s[t] - v;
    }
    __syncthreads();
    if (t < NBINS && hist[t] > 0)
        gbase[t] = t * CAP + atomicAdd(&bin_cnt[t], hist[t]);
    #pragma unroll
    for (int i = 0; i < 16; i++) {
        if (ed[i] >= 0) {
            int b = ed[i] >> 8;
            int lpos = off[b] + atomicAdd(&bump[b], 1);
            stage[lpos] = ((unsigned int)(ed[i] & 255) << 16) | (unsigned int)es[i];
            sbin[lpos] = (unsigned char)b;
        }
    }
    __syncthreads();
    for (int j = t; j < total; j += 256) {
        int b = sbin[j];
        binned[gbase[b] + (j - off[b])] = stage[j];
    }
}

// ---------------- per-bin CSR finalize + x pre-scale: x5 = dinv*x ----------------
__global__ __launch_bounds__(256) void k_csr(const unsigned int* __restrict__ binned,
                                             const int* __restrict__ bin_cnt,
                                             unsigned int* __restrict__ row_ptr,
                                             float* __restrict__ dinv,
                                             unsigned short* __restrict__ csr16,
                                             const float* __restrict__ x,
                                             float* __restrict__ x5) {
    __shared__ int deg[BIN_W];
    __shared__ int off[BIN_W];
    __shared__ int bump[BIN_W];
    int b = blockIdx.x;
    int t = threadIdx.x;
    deg[t] = 0; bump[t] = 0;
    __syncthreads();
    int e0 = b * CAP;
    int e1 = e0 + bin_cnt[b];
    for (int e = e0 + t; e < e1; e += 256)
        atomicAdd(&deg[binned[e] >> 16], 1);
    __syncthreads();
    {
        __shared__ int s[256];
        int v = deg[t];
        s[t] = v; __syncthreads();
        for (int o = 1; o < 256; o <<= 1) {
            int x2 = (t >= o) ? s[t - o] : 0;
            __syncthreads();
            s[t] += x2;
            __syncthreads();
        }
        off[t] = s[t] - v;
    }
    __syncthreads();
    int node = b * BIN_W + t;
    if (node < N_NODES) {
        float di = rsqrtf((float)(deg[t] + 1));
        row_ptr[node] = (unsigned int)(e0 + off[t]) | ((unsigned int)deg[t] << 21);
        dinv[node] = di;
        #pragma unroll
        for (int f = 0; f < 5; f++)
            x5[node * 5 + f] = di * x[node * 5 + f];
    }
    for (int e = e0 + t; e < e1; e += 256) {
        unsigned int v = binned[e];
        int dl = v >> 16;
        int pos = e0 + off[dl] + atomicAdd(&bump[dl], 1);
        csr16[pos] = (unsigned short)(v & 0xffffu);
    }
}

// ---------------- layer 1 fused: agg5 + matmul 5->32, epilogue writes dinv*relu ----------------
__global__ __launch_bounds__(256) void k_layer1(const float* __restrict__ x5,
                                                const unsigned int* __restrict__ row_ptr,
                                                const unsigned short* __restrict__ csr16,
                                                const float* __restrict__ dinv,
                                                const float* __restrict__ W1,
                                                const float* __restrict__ b1,
                                                unsigned short* __restrict__ Hout) {
    __shared__ float A5[32 * 6];
    __shared__ float Ws[160];
    __shared__ float bs[32];
    int t = threadIdx.x;
    int row0 = blockIdx.x * 32;
    if (t < 160) Ws[t] = W1[t];
    if (t >= 224) bs[t - 224] = b1[t - 224];
    int nl = t >> 3, f = t & 7;
    int node = row0 + nl;
    float val = 0.0f;
    float dnode = 0.0f;
    if (node < N_NODES) dnode = dinv[node];
    if (f < 5 && node < N_NODES) {
        float acc0 = x5[node * 5 + f], acc1 = 0.0f;   // self term (pre-scaled)
        unsigned int v = row_ptr[node];
        int e0 = (int)(v & 0x1FFFFFu);
        int e1 = e0 + (int)(v >> 21);
        int e = e0;
        for (; e + 3 < e1; e += 4) {
            int s0 = csr16[e], s1 = csr16[e + 1], s2 = csr16[e + 2], s3 = csr16[e + 3];
            float x0 = x5[s0 * 5 + f], x1 = x5[s1 * 5 + f];
            float x2 = x5[s2 * 5 + f], x3 = x5[s3 * 5 + f];
            acc0 += x0 + x2;
            acc1 += x1 + x3;
        }
        for (; e < e1; e++) acc0 += x5[csr16[e] * 5 + f];
        val = dnode * (acc0 + acc1);
    }
    if (f < 5) A5[nl * 6 + f] = val;
    __syncthreads();
    int j0 = (t & 7) * 4;
    int node2 = row0 + (t >> 3);
    float d2 = (node2 < N_NODES) ? dinv[node2] : 0.0f;
    float a[5];
    #pragma unroll
    for (int k = 0; k < 5; k++) a[k] = A5[(t >> 3) * 6 + k];
    ushort4 o;
    unsigned short* op = (unsigned short*)&o;
    #pragma unroll
    for (int c = 0; c < 4; c++) {
        float acc = bs[j0 + c];
        #pragma unroll
        for (int k = 0; k < 5; k++) acc += a[k] * Ws[k * 32 + j0 + c];
        op[c] = f2bf(d2 * fmaxf(acc, 0.0f));       // hb = dinv * relu(...)
    }
    if (node2 < N_NODES) *(ushort4*)&Hout[(size_t)node2 * 32 + j0] = o;
}

// ---------------- fused layer: gather-aggregate (LDS) + MFMA GEMM ----------------
// Hin holds hb = dinv*h (pre-scaled). SCALE: epilogue multiplies by dinv[row] (layers 1-3).
template<int K, int N, bool SCALE>
__global__ __launch_bounds__(256) void k_fused(const unsigned short* __restrict__ Hin,
                                               const unsigned int* __restrict__ row_ptr,
                                               const unsigned short* __restrict__ csr16,
                                               const float* __restrict__ dinv,
                                               const unsigned short* __restrict__ Wp,
                                               const float* __restrict__ bias,
                                               unsigned short* __restrict__ C) {
    constexpr int KT = K / 32, NT = N / 16, DV = K / 8;
    constexpr int NPB = 2048 / K;     // nodes per block (64/32/16)
    constexpr int TM = NPB / 16;      // M-tiles per block (4/2/1)
    constexpr int KP = K + 8;         // padded row (bf16 units), keeps 16B align
    __shared__ unsigned short As[NPB * KP];
    int t = threadIdx.x;
    int row0 = blockIdx.x * NPB;
    // ---- phase 1: aggregate NPB nodes into LDS (2-deep chain: csr16 -> hb) ----
    {
        int nl = t / DV, f = t % DV;
        int node = row0 + nl;
        const uint4* h4 = (const uint4*)Hin;
        uint4 o = {0u, 0u, 0u, 0u};
        if (node < N_NODES) {
            float di = dinv[node];
            float acc0[8], acc1[8];
            bf8_unpack(h4[(size_t)node * DV + f], acc0);  // self term hb[d]
            #pragma unroll
            for (int i = 0; i < 8; i++) acc1[i] = 0.0f;
            unsigned int rv = row_ptr[node];
            int e0 = (int)(rv & 0x1FFFFFu);
            int e1 = e0 + (int)(rv >> 21);
            int e = e0;
            for (; e + 3 < e1; e += 4) {
                int s0 = csr16[e], s1 = csr16[e + 1], s2 = csr16[e + 2], s3 = csr16[e + 3];
                uint4 u0 = h4[(size_t)s0 * DV + f];
                uint4 u1 = h4[(size_t)s1 * DV + f];
                uint4 u2 = h4[(size_t)s2 * DV + f];
                uint4 u3 = h4[(size_t)s3 * DV + f];
                float t0[8], t1[8], t2[8], t3[8];
                bf8_unpack(u0, t0);
                bf8_unpack(u1, t1);
                bf8_unpack(u2, t2);
                bf8_unpack(u3, t3);
                #pragma unroll
                for (int i = 0; i < 8; i++) {
                    acc0[i] += t0[i] + t2[i];
                    acc1[i] += t1[i] + t3[i];
                }
            }
            for (; e + 1 < e1; e += 2) {
                int s0 = csr16[e], s1 = csr16[e + 1];
                uint4 u0 = h4[(size_t)s0 * DV + f];
                uint4 u1 = h4[(size_t)s1 * DV + f];
                float t0[8], t1[8];
                bf8_unpack(u0, t0);
                bf8_unpack(u1, t1);
                #pragma unroll
                for (int i = 0; i < 8; i++) { acc0[i] += t0[i]; acc1[i] += t1[i]; }
            }
            if (e < e1) {
                float t0[8];
                bf8_unpack(h4[(size_t)csr16[e] * DV + f], t0);
                #pragma unroll
                for (int i = 0; i < 8; i++) acc0[i] += t0[i];
            }
            o.x = pack2(di * (acc0[0] + acc1[0]), di * (acc0[1] + acc1[1]));
            o.y = pack2(di * (acc0[2] + acc1[2]), di * (acc0[3] + acc1[3]));
            o.z = pack2(di * (acc0[4] + acc1[4]), di * (acc0[5] + acc1[5]));
            o.w = pack2(di * (acc0[6] + acc1[6]), di * (acc0[7] + acc1[7]));
        }
        *(uint4*)&As[nl * KP + f * 8] = o;
    }
    __syncthreads();
    // ---- phase 2: MFMA, 4 waves job-split over TM x NT tiles ----
    int wave = t >> 6, lane = t & 63;
    int m = lane & 15, quad = lane >> 4;
    bf16x8 a[TM][KT];
    float dr[TM][4];
    #pragma unroll
    for (int mt = 0; mt < TM; mt++) {
        #pragma unroll
        for (int kt = 0; kt < KT; kt++)
            a[mt][kt] = *(const bf16x8*)&As[(mt * 16 + m) * KP + kt * 32 + quad * 8];
        #pragma unroll
        for (int r = 0; r < 4; r++) {
            int row = row0 + mt * 16 + quad * 4 + r;
            dr[mt][r] = (SCALE && row < N_NODES) ? dinv[row] : 1.0f;
        }
    }
    const bf16x8* Bp = (const bf16x8*)Wp;
    for (int j = wave; j < TM * NT; j += 4) {
        int mt = j % TM, nt = j / TM;
        f32x4 c = {0.f, 0.f, 0.f, 0.f};
        #pragma unroll
        for (int kt = 0; kt < KT; kt++)
            c = __builtin_amdgcn_mfma_f32_16x16x32_bf16(a[mt][kt],
                    Bp[(size_t)(nt * KT + kt) * 64 + lane], c, 0, 0, 0);
        int col = nt * 16 + m;
        float bv = bias[col];
        #pragma unroll
        for (int r = 0; r < 4; r++) {
            int row = row0 + mt * 16 + quad * 4 + r;
            if (row < N_NODES) {
                float v = fmaxf(c[r] + bv, 0.0f);
                if constexpr (SCALE) v *= dr[mt][r];
                C[(size_t)row * N + col] = f2bf(v);
            }
        }
    }
}

// ---------------- pooling (bf16 h, 256 cols), segmented accumulation, 4-row fast path ----------------
#define POOL_CHUNK 64
__global__ void k_poolb(const unsigned short* __restrict__ h, const int* __restrict__ batch,
                        float* pooled) {
    int t = threadIdx.x;                 // feature 0..255
    int n0 = blockIdx.x * POOL_CHUNK;
    int n1 = n0 + POOL_CHUNK; if (n1 > N_NODES) n1 = N_NODES;
    float acc = 0.0f;
    int cur = batch[n0];
    int i = n0;
    while (i + 3 < n1) {
        int g0 = batch[i], g3 = batch[i + 3];
        if (g0 == cur && g3 == cur) {      // fast path: 4 rows, same graph
            float v0 = bf2f(h[(size_t)i * 256 + t]);
            float v1 = bf2f(h[(size_t)(i + 1) * 256 + t]);
            float v2 = bf2f(h[(size_t)(i + 2) * 256 + t]);
            float v3 = bf2f(h[(size_t)(i + 3) * 256 + t]);
            acc += (v0 + v1) + (v2 + v3);
            i += 4;
        } else {
            if (g0 != cur) {
                atomicAdd(&pooled[cur * 256 + t], acc);
                acc = 0.0f; cur = g0;
            }
            acc += bf2f(h[(size_t)i * 256 + t]);
            i++;
        }
    }
    for (; i < n1; i++) {
        int g = batch[i];
        if (g != cur) {
            atomicAdd(&pooled[cur * 256 + t], acc);
            acc = 0.0f; cur = g;
        }
        acc += bf2f(h[(size_t)i * 256 + t]);
    }
    atomicAdd(&pooled[cur * 256 + t], acc);
}

// ---------------- FC + log_softmax (one wave per graph; count via binary search) ----------------
__global__ void k_final(const float* __restrict__ pooled, const int* __restrict__ batch,
                        const float* __restrict__ fcW, const float* __restrict__ fcb,
                        float* __restrict__ out) {
    int g = blockIdx.x;
    int t = threadIdx.x;                 // 0..63
    float cnt = 0.0f;
    if (t == 0) {
        int lo = 0, hi = N_NODES;
        while (lo < hi) { int m = (lo + hi) >> 1; if (batch[m] < g) lo = m + 1; else hi = m; }
        int start = lo;
        lo = 0; hi = N_NODES;
        while (lo < hi) { int m = (lo + hi) >> 1; if (batch[m] < g + 1) lo = m + 1; else hi = m; }
        cnt = (float)(lo - start);
    }
    float inv = 1.0f / fmaxf(__shfl(cnt, 0), 1.0f);
    float p[4];
    #pragma unroll
    for (int m = 0; m < 4; m++) p[m] = pooled[g * 256 + t + 64 * m];
    float logits[NUM_CLASSES];
    #pragma unroll
    for (int j = 0; j < NUM_CLASSES; j++) {
        float s = 0.0f;
        #pragma unroll
        for (int m = 0; m < 4; m++) s += p[m] * fcW[(t + 64 * m) * NUM_CLASSES + j];
        for (int off = 32; off > 0; off >>= 1) s += __shfl_xor(s, off);
        logits[j] = s * inv + fcb[j];
    }
    float mx = logits[0];
    #pragma unroll
    for (int j = 1; j < NUM_CLASSES; j++) mx = fmaxf(mx, logits[j]);
    float se = 0.0f;
    #pragma unroll
    for (int j = 0; j < NUM_CLASSES; j++) se += expf(logits[j] - mx);
    float lse = mx + logf(se);
    if (t < NUM_CLASSES) out[g * NUM_CLASSES + t] = logits[t] - lse;
}

extern "C" void kernel_launch(void* const* d_in, const int* in_sizes, int n_in,
                              void* d_out, int out_size, void* d_ws, size_t ws_size,
                              hipStream_t stream) {
    const float* x     = (const float*)d_in[0];
    const int*   ei    = (const int*)d_in[1];
    const int*   src   = ei;
    const int*   dst   = ei + N_EDGES;
    const int*   batch = (const int*)d_in[2];
    const float* W1 = (const float*)d_in[3];  const float* b1 = (const float*)d_in[4];
    const float* W2 = (const float*)d_in[5];  const float* b2 = (const float*)d_in[6];
    const float* W3 = (const float*)d_in[7];  const float* b3 = (const float*)d_in[8];
    const float* W4 = (const float*)d_in[9];  const float* b4 = (const float*)d_in[10];
    const float* fcW = (const float*)d_in[11]; const float* fcb = (const float*)d_in[12];
    float* out = (float*)d_out;

    char* ws = (char*)d_ws;
    unsigned short* buf1 = (unsigned short*)ws; ws += (size_t)N_NODES * 256 * 2;
    unsigned short* buf2 = (unsigned short*)ws; ws += (size_t)N_NODES * 256 * 2;
    float* dinv     = (float*)ws; ws += (size_t)N_NODES * 4;
    float* x5       = (float*)ws; ws += (size_t)N_NODES * 5 * 4 + 16;
    unsigned int* row_ptr = (unsigned int*)ws; ws += (size_t)(N_NODES + 4) * 4;
    unsigned short* csr16 = (unsigned short*)ws; ws += (size_t)NBINS * CAP * 2;
    unsigned int* binned = (unsigned int*)ws; ws += (size_t)NBINS * CAP * 4;
    int*   bin_cnt  = (int*)ws;   ws += (NBINS + 4) * 4;
    float* pooled   = (float*)ws; ws += (size_t)N_GRAPHS * 256 * 4;
    unsigned short* wp2 = (unsigned short*)ws; ws += 32 * 64 * 2;
    unsigned short* wp3 = (unsigned short*)ws; ws += 64 * 128 * 2;
    unsigned short* wp4 = (unsigned short*)ws; ws += 128 * 256 * 2;

    const int TB = 256;
    k_pre<<<PACK_BLOCKS + INIT_BLOCKS + 1, TB, 0, stream>>>(W2, W3, W4, wp2, wp3, wp4,
                                                            pooled, bin_cnt);
    k_binscatter<<<NCHUNKS, TB, 0, stream>>>(src, dst, bin_cnt, binned);
    k_csr<<<NBINS, TB, 0, stream>>>(binned, bin_cnt, row_ptr, dinv, csr16, x, x5);

    // layer 1: fused agg5 + 5->32 matmul (writes hb1 = dinv*relu)
    k_layer1<<<(N_NODES + 31) / 32, TB, 0, stream>>>(x5, row_ptr, csr16, dinv, W1, b1, buf1);
    // layers 2-4: fused aggregate + MFMA GEMM
    k_fused<32, 64, true><<<(N_NODES + 63) / 64, TB, 0, stream>>>(buf1, row_ptr, csr16, dinv, wp2, b2, buf2);
    k_fused<64, 128, true><<<(N_NODES + 31) / 32, TB, 0, stream>>>(buf2, row_ptr, csr16, dinv, wp3, b3, buf1);
    k_fused<128, 256, false><<<(N_NODES + 15) / 16, TB, 0, stream>>>(buf1, row_ptr, csr16, dinv, wp4, b4, buf2);

    // pooling + classifier
    k_poolb<<<(N_NODES + POOL_CHUNK - 1) / POOL_CHUNK, TB, 0, stream>>>(buf2, batch, pooled);
    k_final<<<N_GRAPHS, 64, 0, stream>>>(pooled, batch, fcW, fcb, out);
}

// Round 14
// 196.682 us; speedup vs baseline: 1.9559x; 1.0652x over previous
//
#include <hip/hip_runtime.h>
#include <hip/hip_bf16.h>
#include <math.h>

#define N_NODES 50000
#define N_EDGES 800000
#define N_GRAPHS 64
#define NUM_CLASSES 10
#define BIN_W 256
#define NBINS ((N_NODES + BIN_W - 1) / BIN_W) // 196
#define CHUNK 4096
#define NCHUNKS ((N_EDGES + CHUNK - 1) / CHUNK) // 196
#define CAP 8192                               // per-bin edge capacity (mean 4082, >60 sigma)
#define PACK_BLOCKS 21
#define INIT_BLOCKS 16

typedef __attribute__((ext_vector_type(8))) short bf16x8;
typedef __attribute__((ext_vector_type(4))) float f32x4;

__device__ inline unsigned short f2bf(float f) {
    unsigned int u = __float_as_uint(f);
    u += 0x7fffu + ((u >> 16) & 1u);
    return (unsigned short)(u >> 16);
}
__device__ inline float bf2f(unsigned short v) {
    return __uint_as_float((unsigned int)v << 16);
}
__device__ inline void bf8_unpack(uint4 v, float* o) {
    o[0] = __uint_as_float(v.x << 16); o[1] = __uint_as_float(v.x & 0xffff0000u);
    o[2] = __uint_as_float(v.y << 16); o[3] = __uint_as_float(v.y & 0xffff0000u);
    o[4] = __uint_as_float(v.z << 16); o[5] = __uint_as_float(v.z & 0xffff0000u);
    o[6] = __uint_as_float(v.w << 16); o[7] = __uint_as_float(v.w & 0xffff0000u);
}
__device__ inline unsigned int pack2(float a, float b) {
    return (unsigned int)f2bf(a) | ((unsigned int)f2bf(b) << 16);
}

// pack W (fp32 KxN row-major) into MFMA B-fragment layout, one 64-lane group per (nt,kt)
template<int K, int N>
__device__ void packW_dev(const float* __restrict__ W, unsigned short* __restrict__ Wp,
                          int bid, int l) {
    constexpr int KT = K / 32;
    int kt = bid % KT, nt = bid / KT;
    int m = l & 15, quad = l >> 4;
    #pragma unroll
    for (int j = 0; j < 8; j++) {
        int k = kt * 32 + quad * 8 + j;
        int n = nt * 16 + m;
        Wp[((size_t)bid * 64 + l) * 8 + j] = f2bf(W[(size_t)k * N + n]);
    }
}

// ---------------- k_pre: weight packing + pooled/bin_cnt init ----------------
__global__ __launch_bounds__(256) void k_pre(const float* __restrict__ W2, const float* __restrict__ W3,
                                             const float* __restrict__ W4,
                                             unsigned short* wp2, unsigned short* wp3, unsigned short* wp4,
                                             float* pooled, int* bin_cnt) {
    int bid = blockIdx.x, t = threadIdx.x;
    if (bid < PACK_BLOCKS) {
        int w = bid * 4 + (t >> 6);
        int lane = t & 63;
        if (w < 4)       packW_dev<32, 64>(W2, wp2, w, lane);
        else if (w < 20) packW_dev<64, 128>(W3, wp3, w - 4, lane);
        else if (w < 84) packW_dev<128, 256>(W4, wp4, w - 20, lane);
    } else if (bid < PACK_BLOCKS + INIT_BLOCKS) {
        int i = (bid - PACK_BLOCKS) * 1024 + t;
        #pragma unroll
        for (int q = 0; q < 4; q++) pooled[i + q * 256] = 0.0f;
    } else {
        if (t < NBINS) bin_cnt[t] = 0;
    }
}

// ---------------- bin-scatter with LDS staging, fixed-capacity bins ----------------
// packed = (dst&255)<<16 | src  (src < 65536)
__global__ __launch_bounds__(256) void k_binscatter(const int* __restrict__ src,
                                                    const int* __restrict__ dst,
                                                    int* bin_cnt,
                                                    unsigned int* __restrict__ binned) {
    __shared__ int hist[NBINS];
    __shared__ int off[NBINS];
    __shared__ int bump[NBINS];
    __shared__ int gbase[NBINS];
    __shared__ unsigned int stage[CHUNK];
    __shared__ unsigned char sbin[CHUNK];
    int t = threadIdx.x;
    int base = blockIdx.x * CHUNK;
    int total = N_EDGES - base; if (total > CHUNK) total = CHUNK;
    for (int i = t; i < NBINS; i += 256) { hist[i] = 0; bump[i] = 0; }
    __syncthreads();
    int es[16], ed[16];
    #pragma unroll
    for (int i = 0; i < 16; i++) {
        int e = base + t + i * 256;
        if (e < N_EDGES) { es[i] = src[e]; ed[i] = dst[e]; }
        else ed[i] = -1;
    }
    #pragma unroll
    for (int i = 0; i < 16; i++)
        if (ed[i] >= 0) atomicAdd(&hist[ed[i] >> 8], 1);
    __syncthreads();
    {
        __shared__ int s[256];
        int v = (t < NBINS) ? hist[t] : 0;
        s[t] = v; __syncthreads();
        for (int o = 1; o < 256; o <<= 1) {
            int x = (t >= o) ? s[t - o] : 0;
            __syncthreads();
            s[t] += x;
            __syncthreads();
        }
        if (t < NBINS) off[t] = s[t] - v;
    }
    __syncthreads();
    if (t < NBINS && hist[t] > 0)
        gbase[t] = t * CAP + atomicAdd(&bin_cnt[t], hist[t]);
    #pragma unroll
    for (int i = 0; i < 16; i++) {
        if (ed[i] >= 0) {
            int b = ed[i] >> 8;
            int lpos = off[b] + atomicAdd(&bump[b], 1);
            stage[lpos] = ((unsigned int)(ed[i] & 255) << 16) | (unsigned int)es[i];
            sbin[lpos] = (unsigned char)b;
        }
    }
    __syncthreads();
    for (int j = t; j < total; j += 256) {
        int b = sbin[j];
        binned[gbase[b] + (j - off[b])] = stage[j];
    }
}

// ---------------- per-bin CSR finalize + x pre-scale: x5 = dinv*x ----------------
__global__ __launch_bounds__(256) void k_csr(const unsigned int* __restrict__ binned,
                                             const int* __restrict__ bin_cnt,
                                             unsigned int* __restrict__ row_ptr,
                                             float* __restrict__ dinv,
                                             unsigned short* __restrict__ csr16,
                                             const float* __restrict__ x,
                                             float* __restrict__ x5) {
    __shared__ int deg[BIN_W];
    __shared__ int off[BIN_W];
    __shared__ int bump[BIN_W];
    int b = blockIdx.x;
    int t = threadIdx.x;
    deg[t] = 0; bump[t] = 0;
    __syncthreads();
    int e0 = b * CAP;
    int e1 = e0 + bin_cnt[b];
    for (int e = e0 + t; e < e1; e += 256)
        atomicAdd(&deg[binned[e] >> 16], 1);
    __syncthreads();
    {
        __shared__ int s[256];
        int v = deg[t];
        s[t] = v; __syncthreads();
        for (int o = 1; o < 256; o <<= 1) {
            int x2 = (t >= o) ? s[t - o] : 0;
            __syncthreads();
            s[t] += x2;
            __syncthreads();
        }
        off[t] = s[t] - v;
    }
    __syncthreads();
    int node = b * BIN_W + t;
    if (node < N_NODES) {
        float di = rsqrtf((float)(deg[t] + 1));
        row_ptr[node] = (unsigned int)(e0 + off[t]) | ((unsigned int)deg[t] << 21);
        dinv[node] = di;
        #pragma unroll
        for (int f = 0; f < 5; f++)
            x5[node * 5 + f] = di * x[node * 5 + f];
    }
    for (int e = e0 + t; e < e1; e += 256) {
        unsigned int v = binned[e];
        int dl = v >> 16;
        int pos = e0 + off[dl] + atomicAdd(&bump[dl], 1);
        csr16[pos] = (unsigned short)(v & 0xffffu);
    }
}

// ---------------- layer 1 fused: agg5 + matmul 5->32, epilogue writes dinv*relu ----------------
__global__ __launch_bounds__(256) void k_layer1(const float* __restrict__ x5,
                                                const unsigned int* __restrict__ row_ptr,
                                                const unsigned short* __restrict__ csr16,
                                                const float* __restrict__ dinv,
                                                const float* __restrict__ W1,
                                                const float* __restrict__ b1,
                                                unsigned short* __restrict__ Hout) {
    __shared__ float A5[32 * 6];
    __shared__ float Ws[160];
    __shared__ float bs[32];
    int t = threadIdx.x;
    int row0 = blockIdx.x * 32;
    if (t < 160) Ws[t] = W1[t];
    if (t >= 224) bs[t - 224] = b1[t - 224];
    int nl = t >> 3, f = t & 7;
    int node = row0 + nl;
    float val = 0.0f;
    float dnode = 0.0f;
    if (node < N_NODES) dnode = dinv[node];
    if (f < 5 && node < N_NODES) {
        float acc0 = x5[node * 5 + f], acc1 = 0.0f;   // self term (pre-scaled)
        unsigned int v = row_ptr[node];
        int e0 = (int)(v & 0x1FFFFFu);
        int e1 = e0 + (int)(v >> 21);
        int e = e0;
        for (; e + 3 < e1; e += 4) {
            int s0 = csr16[e], s1 = csr16[e + 1], s2 = csr16[e + 2], s3 = csr16[e + 3];
            float x0 = x5[s0 * 5 + f], x1 = x5[s1 * 5 + f];
            float x2 = x5[s2 * 5 + f], x3 = x5[s3 * 5 + f];
            acc0 += x0 + x2;
            acc1 += x1 + x3;
        }
        for (; e < e1; e++) acc0 += x5[csr16[e] * 5 + f];
        val = dnode * (acc0 + acc1);
    }
    if (f < 5) A5[nl * 6 + f] = val;
    __syncthreads();
    int j0 = (t & 7) * 4;
    int node2 = row0 + (t >> 3);
    float d2 = (node2 < N_NODES) ? dinv[node2] : 0.0f;
    float a[5];
    #pragma unroll
    for (int k = 0; k < 5; k++) a[k] = A5[(t >> 3) * 6 + k];
    ushort4 o;
    unsigned short* op = (unsigned short*)&o;
    #pragma unroll
    for (int c = 0; c < 4; c++) {
        float acc = bs[j0 + c];
        #pragma unroll
        for (int k = 0; k < 5; k++) acc += a[k] * Ws[k * 32 + j0 + c];
        op[c] = f2bf(d2 * fmaxf(acc, 0.0f));       // hb = dinv * relu(...)
    }
    if (node2 < N_NODES) *(ushort4*)&Hout[(size_t)node2 * 32 + j0] = o;
}

// ---------------- fused layer: gather-aggregate (LDS) + MFMA GEMM (+ fused pool) ----------------
// Hin holds hb = dinv*h (pre-scaled). SCALE: epilogue multiplies by dinv[row] (layers 1-3).
// POOL: epilogue reduces rows in-wave (shfl) and atomically accumulates to pooled; no C write.
template<int K, int N, bool SCALE, bool POOL>
__global__ __launch_bounds__(256) void k_fused(const unsigned short* __restrict__ Hin,
                                               const unsigned int* __restrict__ row_ptr,
                                               const unsigned short* __restrict__ csr16,
                                               const float* __restrict__ dinv,
                                               const unsigned short* __restrict__ Wp,
                                               const float* __restrict__ bias,
                                               unsigned short* __restrict__ C,
                                               const int* __restrict__ batch,
                                               float* __restrict__ pooled) {
    constexpr int KT = K / 32, NT = N / 16, DV = K / 8;
    constexpr int NPB = 2048 / K;     // nodes per block (64/32/16)
    constexpr int TM = NPB / 16;      // M-tiles per block (4/2/1)
    constexpr int KP = K + 8;         // padded row (bf16 units), keeps 16B align
    __shared__ unsigned short As[NPB * KP];
    __shared__ int bb[POOL ? NPB : 4];
    int t = threadIdx.x;
    int row0 = blockIdx.x * NPB;
    if constexpr (POOL) {
        if (t < NPB) bb[t] = batch[min(row0 + t, N_NODES - 1)];
    }
    // ---- phase 1: aggregate NPB nodes into LDS (2-deep chain: csr16 -> hb) ----
    {
        int nl = t / DV, f = t % DV;
        int node = row0 + nl;
        const uint4* h4 = (const uint4*)Hin;
        uint4 o = {0u, 0u, 0u, 0u};
        if (node < N_NODES) {
            float di = dinv[node];
            float acc0[8], acc1[8];
            bf8_unpack(h4[(size_t)node * DV + f], acc0);  // self term hb[d]
            #pragma unroll
            for (int i = 0; i < 8; i++) acc1[i] = 0.0f;
            unsigned int rv = row_ptr[node];
            int e0 = (int)(rv & 0x1FFFFFu);
            int e1 = e0 + (int)(rv >> 21);
            int e = e0;
            for (; e + 3 < e1; e += 4) {
                int s0 = csr16[e], s1 = csr16[e + 1], s2 = csr16[e + 2], s3 = csr16[e + 3];
                uint4 u0 = h4[(size_t)s0 * DV + f];
                uint4 u1 = h4[(size_t)s1 * DV + f];
                uint4 u2 = h4[(size_t)s2 * DV + f];
                uint4 u3 = h4[(size_t)s3 * DV + f];
                float t0[8], t1[8], t2[8], t3[8];
                bf8_unpack(u0, t0);
                bf8_unpack(u1, t1);
                bf8_unpack(u2, t2);
                bf8_unpack(u3, t3);
                #pragma unroll
                for (int i = 0; i < 8; i++) {
                    acc0[i] += t0[i] + t2[i];
                    acc1[i] += t1[i] + t3[i];
                }
            }
            for (; e + 1 < e1; e += 2) {
                int s0 = csr16[e], s1 = csr16[e + 1];
                uint4 u0 = h4[(size_t)s0 * DV + f];
                uint4 u1 = h4[(size_t)s1 * DV + f];
                float t0[8], t1[8];
                bf8_unpack(u0, t0);
                bf8_unpack(u1, t1);
                #pragma unroll
                for (int i = 0; i < 8; i++) { acc0[i] += t0[i]; acc1[i] += t1[i]; }
            }
            if (e < e1) {
                float t0[8];
                bf8_unpack(h4[(size_t)csr16[e] * DV + f], t0);
                #pragma unroll
                for (int i = 0; i < 8; i++) acc0[i] += t0[i];
            }
            o.x = pack2(di * (acc0[0] + acc1[0]), di * (acc0[1] + acc1[1]));
            o.y = pack2(di * (acc0[2] + acc1[2]), di * (acc0[3] + acc1[3]));
            o.z = pack2(di * (acc0[4] + acc1[4]), di * (acc0[5] + acc1[5]));
            o.w = pack2(di * (acc0[6] + acc1[6]), di * (acc0[7] + acc1[7]));
        }
        *(uint4*)&As[nl * KP + f * 8] = o;
    }
    __syncthreads();
    // ---- phase 2: MFMA, 4 waves job-split over TM x NT tiles ----
    int wave = t >> 6, lane = t & 63;
    int m = lane & 15, quad = lane >> 4;
    bf16x8 a[TM][KT];
    float dr[TM][4];
    #pragma unroll
    for (int mt = 0; mt < TM; mt++) {
        #pragma unroll
        for (int kt = 0; kt < KT; kt++)
            a[mt][kt] = *(const bf16x8*)&As[(mt * 16 + m) * KP + kt * 32 + quad * 8];
        #pragma unroll
        for (int r = 0; r < 4; r++) {
            int row = row0 + mt * 16 + quad * 4 + r;
            dr[mt][r] = (SCALE && row < N_NODES) ? dinv[row] : 1.0f;
        }
    }
    const bf16x8* Bp = (const bf16x8*)Wp;
    int g0 = 0, g1 = 0;
    if constexpr (POOL) { g0 = bb[0]; g1 = bb[NPB - 1]; }
    for (int j = wave; j < TM * NT; j += 4) {
        int mt = j % TM, nt = j / TM;
        f32x4 c = {0.f, 0.f, 0.f, 0.f};
        #pragma unroll
        for (int kt = 0; kt < KT; kt++)
            c = __builtin_amdgcn_mfma_f32_16x16x32_bf16(a[mt][kt],
                    Bp[(size_t)(nt * KT + kt) * 64 + lane], c, 0, 0, 0);
        int col = nt * 16 + m;
        float bv = bias[col];
        if constexpr (POOL) {
            float acc0 = 0.0f, acc1 = 0.0f;
            #pragma unroll
            for (int r = 0; r < 4; r++) {
                int rl = mt * 16 + quad * 4 + r;
                int row = row0 + rl;
                if (row < N_NODES) {
                    float v = fmaxf(c[r] + bv, 0.0f);
                    int g = bb[rl];
                    if (g == g0) acc0 += v;
                    else if (g == g1) acc1 += v;
                    else atomicAdd(&pooled[(size_t)g * 256 + col], v);   // statistically never
                }
            }
            acc0 += __shfl_xor(acc0, 32); acc0 += __shfl_xor(acc0, 16);
            acc1 += __shfl_xor(acc1, 32); acc1 += __shfl_xor(acc1, 16);
            if (lane < 16) {
                atomicAdd(&pooled[(size_t)g0 * 256 + col], acc0);
                if (g1 != g0) atomicAdd(&pooled[(size_t)g1 * 256 + col], acc1);
            }
        } else {
            #pragma unroll
            for (int r = 0; r < 4; r++) {
                int row = row0 + mt * 16 + quad * 4 + r;
                if (row < N_NODES) {
                    float v = fmaxf(c[r] + bv, 0.0f);
                    if constexpr (SCALE) v *= dr[mt][r];
                    C[(size_t)row * N + col] = f2bf(v);
                }
            }
        }
    }
}

// ---------------- FC + log_softmax (one wave per graph; count via binary search) ----------------
__global__ void k_final(const float* __restrict__ pooled, const int* __restrict__ batch,
                        const float* __restrict__ fcW, const float* __restrict__ fcb,
                        float* __restrict__ out) {
    int g = blockIdx.x;
    int t = threadIdx.x;                 // 0..63
    float cnt = 0.0f;
    if (t == 0) {
        int lo = 0, hi = N_NODES;
        while (lo < hi) { int m = (lo + hi) >> 1; if (batch[m] < g) lo = m + 1; else hi = m; }
        int start = lo;
        lo = 0; hi = N_NODES;
        while (lo < hi) { int m = (lo + hi) >> 1; if (batch[m] < g + 1) lo = m + 1; else hi = m; }
        cnt = (float)(lo - start);
    }
    float inv = 1.0f / fmaxf(__shfl(cnt, 0), 1.0f);
    float p[4];
    #pragma unroll
    for (int m = 0; m < 4; m++) p[m] = pooled[g * 256 + t + 64 * m];
    float logits[NUM_CLASSES];
    #pragma unroll
    for (int j = 0; j < NUM_CLASSES; j++) {
        float s = 0.0f;
        #pragma unroll
        for (int m = 0; m < 4; m++) s += p[m] * fcW[(t + 64 * m) * NUM_CLASSES + j];
        for (int off = 32; off > 0; off >>= 1) s += __shfl_xor(s, off);
        logits[j] = s * inv + fcb[j];
    }
    float mx = logits[0];
    #pragma unroll
    for (int j = 1; j < NUM_CLASSES; j++) mx = fmaxf(mx, logits[j]);
    float se = 0.0f;
    #pragma unroll
    for (int j = 0; j < NUM_CLASSES; j++) se += expf(logits[j] - mx);
    float lse = mx + logf(se);
    if (t < NUM_CLASSES) out[g * NUM_CLASSES + t] = logits[t] - lse;
}

extern "C" void kernel_launch(void* const* d_in, const int* in_sizes, int n_in,
                              void* d_out, int out_size, void* d_ws, size_t ws_size,
                              hipStream_t stream) {
    const float* x     = (const float*)d_in[0];
    const int*   ei    = (const int*)d_in[1];
    const int*   src   = ei;
    const int*   dst   = ei + N_EDGES;
    const int*   batch = (const int*)d_in[2];
    const float* W1 = (const float*)d_in[3];  const float* b1 = (const float*)d_in[4];
    const float* W2 = (const float*)d_in[5];  const float* b2 = (const float*)d_in[6];
    const float* W3 = (const float*)d_in[7];  const float* b3 = (const float*)d_in[8];
    const float* W4 = (const float*)d_in[9];  const float* b4 = (const float*)d_in[10];
    const float* fcW = (const float*)d_in[11]; const float* fcb = (const float*)d_in[12];
    float* out = (float*)d_out;

    char* ws = (char*)d_ws;
    unsigned short* buf1 = (unsigned short*)ws; ws += (size_t)N_NODES * 256 * 2;
    unsigned short* buf2 = (unsigned short*)ws; ws += (size_t)N_NODES * 256 * 2;
    float* dinv     = (float*)ws; ws += (size_t)N_NODES * 4;
    float* x5       = (float*)ws; ws += (size_t)N_NODES * 5 * 4 + 16;
    unsigned int* row_ptr = (unsigned int*)ws; ws += (size_t)(N_NODES + 4) * 4;
    unsigned short* csr16 = (unsigned short*)ws; ws += (size_t)NBINS * CAP * 2;
    unsigned int* binned = (unsigned int*)ws; ws += (size_t)NBINS * CAP * 4;
    int*   bin_cnt  = (int*)ws;   ws += (NBINS + 4) * 4;
    float* pooled   = (float*)ws; ws += (size_t)N_GRAPHS * 256 * 4;
    unsigned short* wp2 = (unsigned short*)ws; ws += 32 * 64 * 2;
    unsigned short* wp3 = (unsigned short*)ws; ws += 64 * 128 * 2;
    unsigned short* wp4 = (unsigned short*)ws; ws += 128 * 256 * 2;

    const int TB = 256;
    k_pre<<<PACK_BLOCKS + INIT_BLOCKS + 1, TB, 0, stream>>>(W2, W3, W4, wp2, wp3, wp4,
                                                            pooled, bin_cnt);
    k_binscatter<<<NCHUNKS, TB, 0, stream>>>(src, dst, bin_cnt, binned);
    k_csr<<<NBINS, TB, 0, stream>>>(binned, bin_cnt, row_ptr, dinv, csr16, x, x5);

    // layer 1: fused agg5 + 5->32 matmul (writes hb1 = dinv*relu)
    k_layer1<<<(N_NODES + 31) / 32, TB, 0, stream>>>(x5, row_ptr, csr16, dinv, W1, b1, buf1);
    // layers 2-4: fused aggregate + MFMA GEMM (layer 4 also fuses mean-pool accumulation)
    k_fused<32, 64, true, false><<<(N_NODES + 63) / 64, TB, 0, stream>>>(
        buf1, row_ptr, csr16, dinv, wp2, b2, buf2, nullptr, nullptr);
    k_fused<64, 128, true, false><<<(N_NODES + 31) / 32, TB, 0, stream>>>(
        buf2, row_ptr, csr16, dinv, wp3, b3, buf1, nullptr, nullptr);
    k_fused<128, 256, false, true><<<(N_NODES + 15) / 16, TB, 0, stream>>>(
        buf1, row_ptr, csr16, dinv, wp4, b4, nullptr, batch, pooled);

    // classifier
    k_final<<<N_GRAPHS, 64, 0, stream>>>(pooled, batch, fcW, fcb, out);
}